// Round 4
// baseline (2131.673 us; speedup 1.0000x reference)
//
#include <hip/hip_runtime.h>
#include <math.h>

// Problem constants (from setup_inputs: N_data=2000, Lt=10, Q=8, M=256, D=16)
#define NH   2000     // Hankel rows == Y rows
#define QD   8        // latent dim Q
#define DIN  80       // Lt*Q
#define MI   256      // inducing points
#define DOUT 16       // output dim D
#define SIGMA2     1e-3f
#define INV_SIGMA2 1000.0f
#define INV_SIGMA  31.6227766016838f
#define JITTER     1e-4f

// ---------------- zero the accumulator region ----------------
__global__ void k_zero(float* __restrict__ W, int n) {
    int i = blockIdx.x * 256 + threadIdx.x;
    if (i < n) W[i] = 0.f;
}

// ---------------- vbar (mean_n 1/(2Xv+ls2)) + sum(Y^2) ----------------
__global__ void k_prep(const float* __restrict__ Xm_v, const float* __restrict__ Y,
                       const float* __restrict__ ls, float* __restrict__ vbar,
                       float* __restrict__ acc) {
    __shared__ float part[3][DIN];
    __shared__ float red[256];
    int tid = threadIdx.x;
    if (tid < 240) {
        int j = tid % DIN;
        int chunk = tid / DIN;
        int l = j >> 3, qq = j & 7;
        float lsv = ls[j];
        float ls2 = lsv * lsv;
        float s = 0.f;
        int n0 = chunk * 667;
        int n1 = n0 + 667; if (n1 > NH) n1 = NH;
        for (int n = n0; n < n1; ++n) {
            float xv = Xm_v[(1 + n + l) * QD + qq];
            s += 1.0f / (2.0f * xv + ls2);
        }
        part[chunk][j] = s;
    }
    float sy = 0.f;
    for (int i = tid; i < NH * DOUT; i += 256) { float y = Y[i]; sy += y * y; }
    red[tid] = sy;
    __syncthreads();
    if (tid < DIN) vbar[tid] = (part[0][tid] + part[1][tid] + part[2][tid]) * (1.0f / NH);
    for (int st = 128; st > 0; st >>= 1) {
        if (tid < st) red[tid] += red[tid + st];
        __syncthreads();
    }
    if (tid == 0) acc[0] = red[0];
}

// ---------------- psi1[n,a] and Eg[n,a] (one block per n) ----------------
__global__ void k_main(const float* __restrict__ Xm_m, const float* __restrict__ Xm_v,
                       const float* __restrict__ Z, const float* __restrict__ ls,
                       const float* __restrict__ kvp,
                       float* __restrict__ psi1, float* __restrict__ Eg) {
    __shared__ __align__(16) float xm[DIN], h1[DIN], v2[DIN];
    __shared__ float red1[DIN], red2[DIN];
    __shared__ float sc[2];
    int tid = threadIdx.x;
    int n = blockIdx.x;
    if (tid < DIN) {
        int j = tid;
        int l = j >> 3, qq = j & 7;
        int row = 1 + n + l;                       // hankel(v[1:], Lt)
        float xmv = Xm_m[row * QD + qq];
        float xvv = Xm_v[row * QD + qq];
        float lsv = ls[j];
        float ls2 = lsv * lsv;
        float iv1 = 1.0f / (xvv + ls2);
        float iv2 = 1.0f / (2.0f * xvv + ls2);
        xm[j] = xmv; h1[j] = 0.5f * iv1; v2[j] = iv2;
        red1[j] = 0.5f * __logf(ls2 * iv1);                            // logc1 part
        red2[j] = 0.25f * __logf(ls2 * iv2) - 0.5f * xmv * xmv * iv2;  // 0.5*(logc2-base2) part
    }
    __syncthreads();
    if (tid == 0) {
        float a = 0.f, b = 0.f;
        for (int j = 0; j < DIN; ++j) { a += red1[j]; b += red2[j]; }
        sc[0] = a; sc[1] = b;
    }
    __syncthreads();
    float c1 = sc[0], c2h = sc[1];
    const float4* zr  = (const float4*)(Z + tid * DIN);
    const float4* xm4 = (const float4*)xm;
    const float4* h14 = (const float4*)h1;
    const float4* v24 = (const float4*)v2;
    float e1h = 0.f, P = 0.f;
    #pragma unroll 4
    for (int j4 = 0; j4 < DIN / 4; ++j4) {
        float4 z = zr[j4], x = xm4[j4], h = h14[j4], v = v24[j4];
        float d;
        d = z.x - x.x; e1h += h.x * d * d; P += v.x * z.x * (0.25f * z.x - x.x);
        d = z.y - x.y; e1h += h.y * d * d; P += v.y * z.y * (0.25f * z.y - x.y);
        d = z.z - x.z; e1h += h.z * d * d; P += v.z * z.z * (0.25f * z.z - x.z);
        d = z.w - x.w; e1h += h.w * d * d; P += v.w * z.w * (0.25f * z.w - x.w);
    }
    float kv = kvp[0];
    psi1[n * MI + tid] = kv * __expf(c1 - e1h);
    Eg [n * MI + tid] = __expf(c2h - P);
}

// ---------------- Kuu and F = kv^2*exp(-0.25*d2 - C0) ----------------
__global__ void k_kuuF(const float* __restrict__ Z, const float* __restrict__ ls,
                       const float* __restrict__ vbar, const float* __restrict__ kvp,
                       float* __restrict__ Kuu, float* __restrict__ F) {
    __shared__ __align__(16) float ils2[DIN];
    int tid = threadIdx.x;
    int b = blockIdx.x;
    if (tid < DIN) { float l = ls[tid]; ils2[tid] = 1.0f / (l * l); }
    __syncthreads();
    const float4* za4 = (const float4*)(Z + tid * DIN);
    const float4* zb4 = (const float4*)(Z + b * DIN);
    const float4* il4 = (const float4*)ils2;
    const float4* vb4 = (const float4*)vbar;
    float d2a = 0.f, c0 = 0.f;
    #pragma unroll 4
    for (int j4 = 0; j4 < DIN / 4; ++j4) {
        float4 za = za4[j4], zb = zb4[j4], il = il4[j4], vb = vb4[j4];
        float d;
        d = za.x - zb.x; d2a += d * d * il.x; c0 += vb.x * za.x * zb.x;
        d = za.y - zb.y; d2a += d * d * il.y; c0 += vb.y * za.y * zb.y;
        d = za.z - zb.z; d2a += d * d * il.z; c0 += vb.z * za.z * zb.z;
        d = za.w - zb.w; d2a += d * d * il.w; c0 += vb.w * za.w * zb.w;
    }
    float kv = kvp[0];
    int a = tid;
    Kuu[b * MI + a] = kv * __expf(-0.5f * d2a) + (a == b ? JITTER : 0.f);
    F  [b * MI + a] = kv * kv * __expf(-0.25f * d2a - 0.5f * c0);
}

// ---------------- S_part[y] = partial Eg^T Eg (64x64 tiles, split-K=5) ----------------
__global__ void k_syrk(const float* __restrict__ Eg, float* __restrict__ Spart) {
    __shared__ __align__(16) float As[16 * 64], Bs[16 * 64];
    int tid = threadIdx.x;
    int ta = blockIdx.x & 3, tb = blockIdx.x >> 2;
    int k0 = blockIdx.y * 400;
    int tx = tid & 15, ty = tid >> 4;
    float acc[4][4] = {};
    for (int kk = k0; kk < k0 + 400; kk += 16) {
        __syncthreads();
        for (int i = tid; i < 1024; i += 256) {
            int k = i >> 6, c = i & 63;
            As[k * 64 + c] = Eg[(kk + k) * MI + 64 * ta + c];
            Bs[k * 64 + c] = Eg[(kk + k) * MI + 64 * tb + c];
        }
        __syncthreads();
        #pragma unroll
        for (int k = 0; k < 16; ++k) {
            float4 a4 = *(const float4*)&As[k * 64 + 4 * tx];
            float4 b4 = *(const float4*)&Bs[k * 64 + 4 * ty];
            float a[4] = {a4.x, a4.y, a4.z, a4.w};
            float b[4] = {b4.x, b4.y, b4.z, b4.w};
            #pragma unroll
            for (int i = 0; i < 4; ++i)
                #pragma unroll
                for (int j = 0; j < 4; ++j)
                    acc[i][j] += a[i] * b[j];
        }
    }
    float* out = Spart + blockIdx.y * (MI * MI);
    #pragma unroll
    for (int i = 0; i < 4; ++i)
        #pragma unroll
        for (int j = 0; j < 4; ++j)
            out[(64 * ta + 4 * tx + i) * MI + 64 * tb + 4 * ty + j] = acc[i][j];
}

// ---------------- P2 (=psi2) = F * sum_y Spart ----------------
__global__ void k_psi2(const float* __restrict__ F, const float* __restrict__ Spart,
                       float* __restrict__ S) {
    int i = blockIdx.x * 256 + threadIdx.x;
    float s = Spart[i] + Spart[MI * MI + i] + Spart[2 * MI * MI + i]
            + Spart[3 * MI * MI + i] + Spart[4 * MI * MI + i];
    S[i] = F[i] * s;
}

// ---------------- G += psi1^T Y ----------------
__global__ void k_G(const float* __restrict__ psi1, const float* __restrict__ Y,
                    float* __restrict__ G) {
    int a = threadIdx.x;
    int n0 = blockIdx.x * 125;
    float acc[DOUT] = {};
    for (int n = n0; n < n0 + 125; ++n) {
        float p = psi1[n * MI + a];
        #pragma unroll
        for (int d = 0; d < DOUT; ++d) acc[d] += p * Y[n * DOUT + d];
    }
    #pragma unroll
    for (int d = 0; d < DOUT; ++d) atomicAdd(&G[a * DOUT + d], acc[d]);
}

// ---------------- single-workgroup 256x256 Cholesky (register tiled) ----------------
// NOTE 1: all indexing into the per-thread tile t[][] must be compile-time
// static — dynamic j-index forced the array to scratch (round 1: 4 ms).
// NOTE 2: __launch_bounds__(1024,4) sets only the MIN of amdgpu-waves-per-eu;
// the backend still targeted 8 waves/EU (64-VGPR cap) and spilled (rounds
// 2-3: VGPR=56, 426 us). amdgpu_waves_per_eu(4,4) pins min=max=4 ->
// 128-VGPR budget. Single-workgroup kernel, so 1 block/CU costs nothing.
__global__ __launch_bounds__(1024)
__attribute__((amdgpu_waves_per_eu(4, 4)))
void k_chol(const float* __restrict__ Ain,
        float* __restrict__ Ltout, float* __restrict__ accbuf, int logdetFlag) {
    __shared__ float col[2][MI];
    __shared__ float ldred[32];
    int tid = threadIdx.x;
    int tc = tid & 31, tr = tid >> 5;     // thread owns rows tr+32i, cols tc+32j
    float t[8][8];
    #pragma unroll
    for (int i = 0; i < 8; ++i)
        #pragma unroll
        for (int j = 0; j < 8; ++j)
            t[i][j] = Ain[(tr + 32 * i) * MI + tc + 32 * j];
    if (tc == 0) {
        #pragma unroll
        for (int i = 0; i < 8; ++i) col[0][tr + 32 * i] = t[i][0];
    }
    __syncthreads();
    for (int k = 0; k < MI; ++k) {
        int p = k & 1;
        float dk = col[p][k];             // unscaled pivot
        float s = sqrtf(dk);
        float inv = 1.0f / dk;
        float isq = s * inv;              // 1/s
        float ar[8], bc[8];
        #pragma unroll
        for (int i = 0; i < 8; ++i) { int r = tr + 32 * i; ar[i] = (r > k) ? col[p][r] * inv : 0.f; }
        #pragma unroll
        for (int j = 0; j < 8; ++j) { int c = tc + 32 * j; bc[j] = (c > k) ? col[p][c] : 0.f; }
        #pragma unroll
        for (int i = 0; i < 8; ++i)
            #pragma unroll
            for (int j = 0; j < 8; ++j)
                t[i][j] = fmaf(-ar[i], bc[j], t[i][j]);
        // scale column k to final L values; publish next unscaled column.
        #pragma unroll
        for (int j = 0; j < 8; ++j) {
            int c = tc + 32 * j;
            if (c == k) {
                #pragma unroll
                for (int i = 0; i < 8; ++i) {
                    int r = tr + 32 * i;
                    if (r > k)       t[i][j] *= isq;
                    else if (r == k) t[i][j] = s;
                }
            }
            if (c == k + 1) {             // k+1 < MI implied by c range
                #pragma unroll
                for (int i = 0; i < 8; ++i) {
                    int r = tr + 32 * i;
                    if (r > k) col[1 - p][r] = t[i][j];
                }
            }
        }
        __syncthreads();
    }
    // store L transposed only (the only consumer besides logdet)
    #pragma unroll
    for (int i = 0; i < 8; ++i) {
        int r = tr + 32 * i;
        #pragma unroll
        for (int j = 0; j < 8; ++j) {
            int c = tc + 32 * j;
            float v = (c <= r) ? t[i][j] : 0.f;
            Ltout[c * MI + r] = v;
        }
    }
    if (logdetFlag) {
        if (tr == tc) {
            float ld = 0.f;
            #pragma unroll
            for (int i = 0; i < 8; ++i) ld += 2.0f * __logf(t[i][i]);
            ldred[tr] = ld;
        }
        __syncthreads();
        if (tid == 0) {
            float s2 = 0.f;
            for (int i = 0; i < 32; ++i) s2 += ldred[i];
            accbuf[2] = s2;
        }
    }
}

// ---------------- triangular inverse: Linv = L^-1 (reads Lt), 32 cols/block ----------------
__global__ void k_trinv(const float* __restrict__ Lt, float* __restrict__ Linv) {
    __shared__ float X[MI * 32];
    int tid = threadIdx.x;          // 512 threads
    int j0 = blockIdx.x * 32;
    for (int i = tid; i < MI * 32; i += 512) X[i] = 0.f;
    __syncthreads();
    if (tid < 32) X[(j0 + tid) * 32 + tid] = 1.0f;
    __syncthreads();
    int jl = tid & 31, trr = tid >> 5;   // 16 row-groups
    for (int i = j0; i < MI; ++i) {
        float dinv = 1.0f / Lt[i * MI + i];
        if (tid < 32) X[i * 32 + tid] *= dinv;
        __syncthreads();
        float xi = X[i * 32 + jl];
        for (int r = i + 1 + trr; r < MI; r += 16)
            X[r * 32 + jl] -= Lt[i * MI + r] * xi;
        __syncthreads();
    }
    for (int i = tid; i < MI * 32; i += 512) {
        int r = i >> 5, c = i & 31;
        Linv[r * MI + j0 + c] = X[i];
    }
}

// ---------------- T = Linv * P2  (NN, 64x64 tiles) ----------------
__global__ void k_gemm1(const float* __restrict__ A, const float* __restrict__ S,
                        float* __restrict__ T) {
    __shared__ __align__(16) float As[16 * 68], Bs[16 * 68];
    int tid = threadIdx.x;
    int ta = blockIdx.x & 3, tb = blockIdx.x >> 2;
    int tx = tid & 15, ty = tid >> 4;
    float acc[4][4] = {};
    for (int k0 = 0; k0 < MI; k0 += 16) {
        __syncthreads();
        for (int i = tid; i < 1024; i += 256) {
            int r = i >> 4, kk = i & 15;
            As[kk * 68 + r] = A[(64 * ta + r) * MI + k0 + kk];
        }
        for (int i = tid; i < 1024; i += 256) {
            int k = i >> 6, c = i & 63;
            Bs[k * 68 + c] = S[(k0 + k) * MI + 64 * tb + c];
        }
        __syncthreads();
        #pragma unroll
        for (int k = 0; k < 16; ++k) {
            float4 a4 = *(const float4*)&As[k * 68 + 4 * tx];
            float4 b4 = *(const float4*)&Bs[k * 68 + 4 * ty];
            float a[4] = {a4.x, a4.y, a4.z, a4.w};
            float b[4] = {b4.x, b4.y, b4.z, b4.w};
            #pragma unroll
            for (int i = 0; i < 4; ++i)
                #pragma unroll
                for (int j = 0; j < 4; ++j)
                    acc[i][j] += a[i] * b[j];
        }
    }
    #pragma unroll
    for (int i = 0; i < 4; ++i)
        #pragma unroll
        for (int j = 0; j < 4; ++j)
            T[(64 * ta + 4 * tx + i) * MI + 64 * tb + 4 * ty + j] = acc[i][j];
}

// ---------------- Bm = T * Linv^T / sigma2 + I ; trace(AAT) via diag atomics ----------------
__global__ void k_gemm2(const float* __restrict__ T, const float* __restrict__ Linv,
                        float* __restrict__ Bm, float* __restrict__ accbuf) {
    __shared__ __align__(16) float As[16 * 68], Bs[16 * 68];
    int tid = threadIdx.x;
    int ta = blockIdx.x & 3, tb = blockIdx.x >> 2;
    int tx = tid & 15, ty = tid >> 4;
    float acc[4][4] = {};
    for (int k0 = 0; k0 < MI; k0 += 16) {
        __syncthreads();
        for (int i = tid; i < 1024; i += 256) {
            int r = i >> 4, kk = i & 15;
            As[kk * 68 + r] = T[(64 * ta + r) * MI + k0 + kk];
            Bs[kk * 68 + r] = Linv[(64 * tb + r) * MI + k0 + kk];
        }
        __syncthreads();
        #pragma unroll
        for (int k = 0; k < 16; ++k) {
            float4 a4 = *(const float4*)&As[k * 68 + 4 * tx];
            float4 b4 = *(const float4*)&Bs[k * 68 + 4 * ty];
            float a[4] = {a4.x, a4.y, a4.z, a4.w};
            float b[4] = {b4.x, b4.y, b4.z, b4.w};
            #pragma unroll
            for (int i = 0; i < 4; ++i)
                #pragma unroll
                for (int j = 0; j < 4; ++j)
                    acc[i][j] += a[i] * b[j];
        }
    }
    #pragma unroll
    for (int i = 0; i < 4; ++i)
        #pragma unroll
        for (int j = 0; j < 4; ++j) {
            int gr = 64 * ta + 4 * tx + i, gc = 64 * tb + 4 * ty + j;
            float v = acc[i][j] * INV_SIGMA2;
            if (gr == gc) atomicAdd(&accbuf[1], v);
            Bm[gr * MI + gc] = v + (gr == gc ? 1.0f : 0.f);
        }
}

// ---------------- AY = Linv * G / sigma ----------------
__global__ void k_AY(const float* __restrict__ Linv, const float* __restrict__ G,
                     float* __restrict__ AY) {
    int gid = blockIdx.x * 256 + threadIdx.x;
    int m = gid >> 4, d = gid & 15;
    float s = 0.f;
    for (int k = 0; k < MI; ++k) s += Linv[m * MI + k] * G[k * DOUT + d];
    AY[m * DOUT + d] = s * INV_SIGMA;
}

// ---------------- c = LBinv*AY/sigma ; assemble bound ----------------
__global__ void k_final(const float* __restrict__ LBinv, const float* __restrict__ AY,
                        const float* __restrict__ accbuf, const float* __restrict__ kvp,
                        float* __restrict__ out) {
    __shared__ float AYs[MI * DOUT];
    __shared__ float red[256];
    int tid = threadIdx.x;
    for (int i = tid; i < MI * DOUT; i += 256) AYs[i] = AY[i];
    __syncthreads();
    float crow[DOUT] = {};
    const float4* lrow4 = (const float4*)(LBinv + tid * MI);
    for (int k4 = 0; k4 < MI / 4; ++k4) {
        float4 l = lrow4[k4];
        const float* ay0 = &AYs[(4 * k4) * DOUT];
        #pragma unroll
        for (int d = 0; d < DOUT; ++d)
            crow[d] += l.x * ay0[d] + l.y * ay0[DOUT + d] + l.z * ay0[2 * DOUT + d] + l.w * ay0[3 * DOUT + d];
    }
    float c2 = 0.f;
    #pragma unroll
    for (int d = 0; d < DOUT; ++d) { float cd = crow[d] * INV_SIGMA; c2 += cd * cd; }
    red[tid] = c2;
    __syncthreads();
    for (int st = 128; st > 0; st >>= 1) {
        if (tid < st) red[tid] += red[tid + st];
        __syncthreads();
    }
    if (tid == 0) {
        float kv = kvp[0];
        float psi0 = (float)NH * kv;
        float sumY2 = accbuf[0], trace = accbuf[1], logdet = accbuf[2];
        float bound = -0.5f * (float)(NH * DOUT) * __logf(6.28318530717959f * SIGMA2)
                      - 0.5f * INV_SIGMA2 * sumY2
                      - 0.5f * (float)DOUT * (psi0 * INV_SIGMA2 - trace)
                      - 0.5f * (float)DOUT * logdet
                      + 0.5f * red[0];
        out[0] = bound;
    }
}

extern "C" void kernel_launch(void* const* d_in, const int* in_sizes, int n_in,
                              void* d_out, int out_size, void* d_ws, size_t ws_size,
                              hipStream_t stream) {
    (void)in_sizes; (void)n_in; (void)out_size; (void)ws_size;
    const float* Xm_m = (const float*)d_in[0];
    const float* Xm_v = (const float*)d_in[1];
    const float* Z    = (const float*)d_in[2];
    const float* Y    = (const float*)d_in[3];
    const float* kvp  = (const float*)d_in[4];
    const float* ls   = (const float*)d_in[5];
    float* out = (float*)d_out;
    float* W = (float*)d_ws;

    float* acc   = W;              // 16
    float* S     = W + 16;         // 65536 (final psi2 = F*sum(Spart))
    float* G     = W + 65552;      // 4096
    float* vbar  = W + 69664;      // 80
    float* psi1  = W + 69760;      // 512000
    float* Eg    = W + 581760;     // 512000
    float* Kuu   = W + 1093760;    // 65536
    float* F     = W + 1159296;    // 65536
    float* Lt    = W + 1290368;    // 65536
    float* Linv  = W + 1355904;    // 65536
    float* T     = W + 1421440;    // 65536
    float* Bm    = W + 1486976;    // 65536
    float* LBt   = W + 1618048;    // 65536
    float* LBinv = W + 1683584;    // 65536
    float* AY    = W + 1749120;    // 4096
    float* Spart = W + 1753216;    // 5*65536   (end ~8.3 MB)

    k_zero<<<273, 256, 0, stream>>>(W, 69648);                 // acc, S, G
    k_prep<<<1, 256, 0, stream>>>(Xm_v, Y, ls, vbar, acc);
    k_main<<<NH, 256, 0, stream>>>(Xm_m, Xm_v, Z, ls, kvp, psi1, Eg);
    k_kuuF<<<MI, 256, 0, stream>>>(Z, ls, vbar, kvp, Kuu, F);
    k_syrk<<<dim3(16, 5), 256, 0, stream>>>(Eg, Spart);
    k_psi2<<<MI, 256, 0, stream>>>(F, Spart, S);
    k_G<<<16, 256, 0, stream>>>(psi1, Y, G);
    k_chol<<<1, 1024, 0, stream>>>(Kuu, Lt, acc, 0);
    k_trinv<<<8, 512, 0, stream>>>(Lt, Linv);
    k_gemm1<<<16, 256, 0, stream>>>(Linv, S, T);
    k_gemm2<<<16, 256, 0, stream>>>(T, Linv, Bm, acc);
    k_AY<<<16, 256, 0, stream>>>(Linv, G, AY);
    k_chol<<<1, 1024, 0, stream>>>(Bm, LBt, acc, 1);
    k_trinv<<<8, 512, 0, stream>>>(LBt, LBinv);
    k_final<<<1, 256, 0, stream>>>(LBinv, AY, acc, kvp, out);
}

// Round 5
// 848.882 us; speedup vs baseline: 2.5112x; 2.5112x over previous
//
#include <hip/hip_runtime.h>
#include <math.h>

// Problem constants (from setup_inputs: N_data=2000, Lt=10, Q=8, M=256, D=16)
#define NH   2000     // Hankel rows == Y rows
#define QD   8        // latent dim Q
#define DIN  80       // Lt*Q
#define MI   256      // inducing points
#define DOUT 16       // output dim D
#define SIGMA2     1e-3f
#define INV_SIGMA2 1000.0f
#define JITTER     1e-4f

// HARD-WON NOTES (rounds 1-4):
//  - per-thread arrays indexed dynamically -> scratch (4 ms).
//  - even static-indexed 64-float/thread tiles across barriered loops get
//    spilled by the allocator regardless of __launch_bounds__ /
//    amdgpu_waves_per_eu (VGPR stuck at 56, ~426 us of L1/L2 scratch BW on
//    ONE CU). Monolithic register-tiled 256x256 factorizations are a dead
//    end on gfx950 -> use blocked LDS-resident panels instead.

// ---------------- zero acc + G + LinvK + LinvM ----------------
__global__ void k_zero(float* __restrict__ W, int n) {
    int i = blockIdx.x * 256 + threadIdx.x;
    if (i < n) W[i] = 0.f;
}

// ---------------- vbar (mean_n 1/(2Xv+ls2)) + sum(Y^2) ----------------
__global__ void k_prep(const float* __restrict__ Xm_v, const float* __restrict__ Y,
                       const float* __restrict__ ls, float* __restrict__ vbar,
                       float* __restrict__ acc) {
    __shared__ float part[3][DIN];
    __shared__ float red[256];
    int tid = threadIdx.x;
    if (tid < 240) {
        int j = tid % DIN;
        int chunk = tid / DIN;
        int l = j >> 3, qq = j & 7;
        float lsv = ls[j];
        float ls2 = lsv * lsv;
        float s = 0.f;
        int n0 = chunk * 667;
        int n1 = n0 + 667; if (n1 > NH) n1 = NH;
        for (int n = n0; n < n1; ++n) {
            float xv = Xm_v[(1 + n + l) * QD + qq];
            s += 1.0f / (2.0f * xv + ls2);
        }
        part[chunk][j] = s;
    }
    float sy = 0.f;
    for (int i = tid; i < NH * DOUT; i += 256) { float y = Y[i]; sy += y * y; }
    red[tid] = sy;
    __syncthreads();
    if (tid < DIN) vbar[tid] = (part[0][tid] + part[1][tid] + part[2][tid]) * (1.0f / NH);
    for (int st = 128; st > 0; st >>= 1) {
        if (tid < st) red[tid] += red[tid + st];
        __syncthreads();
    }
    if (tid == 0) acc[0] = red[0];
}

// ---------------- psi1[n,a] and Eg[n,a] (one block per n) ----------------
__global__ void k_main(const float* __restrict__ Xm_m, const float* __restrict__ Xm_v,
                       const float* __restrict__ Z, const float* __restrict__ ls,
                       const float* __restrict__ kvp,
                       float* __restrict__ psi1, float* __restrict__ Eg) {
    __shared__ __align__(16) float xm[DIN], h1[DIN], v2[DIN];
    __shared__ float red1[DIN], red2[DIN];
    __shared__ float sc[2];
    int tid = threadIdx.x;
    int n = blockIdx.x;
    if (tid < DIN) {
        int j = tid;
        int l = j >> 3, qq = j & 7;
        int row = 1 + n + l;                       // hankel(v[1:], Lt)
        float xmv = Xm_m[row * QD + qq];
        float xvv = Xm_v[row * QD + qq];
        float lsv = ls[j];
        float ls2 = lsv * lsv;
        float iv1 = 1.0f / (xvv + ls2);
        float iv2 = 1.0f / (2.0f * xvv + ls2);
        xm[j] = xmv; h1[j] = 0.5f * iv1; v2[j] = iv2;
        red1[j] = 0.5f * __logf(ls2 * iv1);                            // logc1 part
        red2[j] = 0.25f * __logf(ls2 * iv2) - 0.5f * xmv * xmv * iv2;  // 0.5*(logc2-base2)
    }
    __syncthreads();
    if (tid == 0) {
        float a = 0.f, b = 0.f;
        for (int j = 0; j < DIN; ++j) { a += red1[j]; b += red2[j]; }
        sc[0] = a; sc[1] = b;
    }
    __syncthreads();
    float c1 = sc[0], c2h = sc[1];
    const float4* zr  = (const float4*)(Z + tid * DIN);
    const float4* xm4 = (const float4*)xm;
    const float4* h14 = (const float4*)h1;
    const float4* v24 = (const float4*)v2;
    float e1h = 0.f, P = 0.f;
    #pragma unroll 4
    for (int j4 = 0; j4 < DIN / 4; ++j4) {
        float4 z = zr[j4], x = xm4[j4], h = h14[j4], v = v24[j4];
        float d;
        d = z.x - x.x; e1h += h.x * d * d; P += v.x * z.x * (0.25f * z.x - x.x);
        d = z.y - x.y; e1h += h.y * d * d; P += v.y * z.y * (0.25f * z.y - x.y);
        d = z.z - x.z; e1h += h.z * d * d; P += v.z * z.z * (0.25f * z.z - x.z);
        d = z.w - x.w; e1h += h.w * d * d; P += v.w * z.w * (0.25f * z.w - x.w);
    }
    float kv = kvp[0];
    psi1[n * MI + tid] = kv * __expf(c1 - e1h);
    Eg [n * MI + tid] = __expf(c2h - P);
}

// ---------------- Kuu and F = kv^2*exp(-0.25*d2 - 0.5*C0) ----------------
__global__ void k_kuuF(const float* __restrict__ Z, const float* __restrict__ ls,
                       const float* __restrict__ vbar, const float* __restrict__ kvp,
                       float* __restrict__ Kuu, float* __restrict__ F) {
    __shared__ __align__(16) float ils2[DIN];
    int tid = threadIdx.x;
    int b = blockIdx.x;
    if (tid < DIN) { float l = ls[tid]; ils2[tid] = 1.0f / (l * l); }
    __syncthreads();
    const float4* za4 = (const float4*)(Z + tid * DIN);
    const float4* zb4 = (const float4*)(Z + b * DIN);
    const float4* il4 = (const float4*)ils2;
    const float4* vb4 = (const float4*)vbar;
    float d2a = 0.f, c0 = 0.f;
    #pragma unroll 4
    for (int j4 = 0; j4 < DIN / 4; ++j4) {
        float4 za = za4[j4], zb = zb4[j4], il = il4[j4], vb = vb4[j4];
        float d;
        d = za.x - zb.x; d2a += d * d * il.x; c0 += vb.x * za.x * zb.x;
        d = za.y - zb.y; d2a += d * d * il.y; c0 += vb.y * za.y * zb.y;
        d = za.z - zb.z; d2a += d * d * il.z; c0 += vb.z * za.z * zb.z;
        d = za.w - zb.w; d2a += d * d * il.w; c0 += vb.w * za.w * zb.w;
    }
    float kv = kvp[0];
    int a = tid;
    Kuu[b * MI + a] = kv * __expf(-0.5f * d2a) + (a == b ? JITTER : 0.f);
    F  [b * MI + a] = kv * kv * __expf(-0.25f * d2a - 0.5f * c0);
}

// ---------------- S_part[y] = partial Eg^T Eg (64x64 tiles, split-K=5) ------
__global__ void k_syrk(const float* __restrict__ Eg, float* __restrict__ Spart) {
    __shared__ __align__(16) float As[16 * 64], Bs[16 * 64];
    int tid = threadIdx.x;
    int ta = blockIdx.x & 3, tb = blockIdx.x >> 2;
    int k0 = blockIdx.y * 400;
    int tx = tid & 15, ty = tid >> 4;
    float acc[4][4] = {};
    for (int kk = k0; kk < k0 + 400; kk += 16) {
        __syncthreads();
        for (int i = tid; i < 1024; i += 256) {
            int k = i >> 6, c = i & 63;
            As[k * 64 + c] = Eg[(kk + k) * MI + 64 * ta + c];
            Bs[k * 64 + c] = Eg[(kk + k) * MI + 64 * tb + c];
        }
        __syncthreads();
        #pragma unroll
        for (int k = 0; k < 16; ++k) {
            float4 a4 = *(const float4*)&As[k * 64 + 4 * tx];
            float4 b4 = *(const float4*)&Bs[k * 64 + 4 * ty];
            float a[4] = {a4.x, a4.y, a4.z, a4.w};
            float b[4] = {b4.x, b4.y, b4.z, b4.w};
            #pragma unroll
            for (int i = 0; i < 4; ++i)
                #pragma unroll
                for (int j = 0; j < 4; ++j)
                    acc[i][j] += a[i] * b[j];
        }
    }
    float* out = Spart + blockIdx.y * (MI * MI);
    #pragma unroll
    for (int i = 0; i < 4; ++i)
        #pragma unroll
        for (int j = 0; j < 4; ++j)
            out[(64 * ta + 4 * tx + i) * MI + 64 * tb + 4 * ty + j] = acc[i][j];
}

// ---------------- S(=psi2) = F * sum_y Spart ; M2 = Kuu + S/sigma2 ----------
__global__ void k_psi2M(const float* __restrict__ F, const float* __restrict__ Spart,
                        const float* __restrict__ Kuu,
                        float* __restrict__ S, float* __restrict__ M2) {
    int i = blockIdx.x * 256 + threadIdx.x;
    float s = Spart[i] + Spart[MI * MI + i] + Spart[2 * MI * MI + i]
            + Spart[3 * MI * MI + i] + Spart[4 * MI * MI + i];
    float v = F[i] * s;
    S[i] = v;
    M2[i] = Kuu[i] + INV_SIGMA2 * v;
}

// ---------------- G += psi1^T Y ----------------
__global__ void k_G(const float* __restrict__ psi1, const float* __restrict__ Y,
                    float* __restrict__ G) {
    int a = threadIdx.x;
    int n0 = blockIdx.x * 125;
    float acc[DOUT] = {};
    for (int n = n0; n < n0 + 125; ++n) {
        float p = psi1[n * MI + a];
        #pragma unroll
        for (int d = 0; d < DOUT; ++d) acc[d] += p * Y[n * DOUT + d];
    }
    #pragma unroll
    for (int d = 0; d < DOUT; ++d) atomicAdd(&G[a * DOUT + d], acc[d]);
}

// ---------------- panel Cholesky (cols [64p,64p+64), rows [64p,256)) --------
// LDS-resident, column-major P[c*H+r]; batched over {Kuu, M2} via blockIdx.x.
// Diag entries written straight to global inside the loop; logdet accumulated
// by thread 0 (it reads the pivot anyway). 2 barriers/pivot, no big register
// arrays -> no scratch.
__global__ void k_cholp(float* __restrict__ AK, float* __restrict__ AM,
                        float* __restrict__ acc, int p) {
    float* A = blockIdx.x ? AM : AK;
    const int c0 = 64 * p, H = 256 - c0;
    __shared__ float P[64 * 256];            // 64 KB max (p=0)
    int tid = threadIdx.x;                   // 512 threads
    int r = tid >> 1, h = tid & 1;
    if (r < H) {
        const float* arow = A + (c0 + r) * MI + c0;
        for (int c = 32 * h; c < 32 * h + 32; ++c) P[c * H + r] = arow[c];
    }
    __syncthreads();
    float lgsum = 0.f;
    for (int kk = 0; kk < 64; ++kk) {
        float piv = P[kk * H + kk];          // final since prev iter's barrier
        float is = rsqrtf(piv);
        if (tid == 0) { lgsum += __logf(piv); A[(c0 + kk) * MI + c0 + kk] = piv * is; }
        if (h == 0 && r > kk && r < H) P[kk * H + r] *= is;  // scale col kk (r>kk only)
        __syncthreads();
        if (r > kk && r < H) {
            float m = P[kk * H + r];
            for (int c = kk + 1 + h; c < 64; c += 2)
                P[c * H + r] = fmaf(-m, P[kk * H + c], P[c * H + r]);
        }
        __syncthreads();
    }
    if (r < H) {
        for (int c = 32 * h; c < 32 * h + 32; ++c)
            if (r > c) A[(c0 + r) * MI + c0 + c] = P[c * H + r];
    }
    if (tid == 0) atomicAdd(&acc[2 + blockIdx.x], lgsum);
}

// ---------------- trailing update: A22 -= Lp * Lp^T (64x64x64 tiles) --------
__global__ void k_cholu(float* __restrict__ AK, float* __restrict__ AM, int p) {
    float* A = blockIdx.y ? AM : AK;
    int t0 = 64 * (p + 1);
    int idx = blockIdx.x, ti = 0;
    while (idx > ti) { idx -= ti + 1; ti++; }
    int tj = idx;                            // lower tiles ti >= tj
    int R0 = t0 + 64 * ti, C0 = t0 + 64 * tj, K0 = 64 * p;
    __shared__ float As[64 * 68], Bs[64 * 68];
    int tid = threadIdx.x;
    int tx = tid & 15, ty = tid >> 4;
    for (int q = tid; q < 4096; q += 256) {
        int rr = q >> 6, k = q & 63;
        As[k * 68 + rr] = A[(R0 + rr) * MI + K0 + k];
        Bs[k * 68 + rr] = A[(C0 + rr) * MI + K0 + k];
    }
    __syncthreads();
    float acc[4][4] = {};
    #pragma unroll 4
    for (int k = 0; k < 64; ++k) {
        float4 a4 = *(const float4*)&As[k * 68 + 4 * tx];
        float4 b4 = *(const float4*)&Bs[k * 68 + 4 * ty];
        float a[4] = {a4.x, a4.y, a4.z, a4.w};
        float b[4] = {b4.x, b4.y, b4.z, b4.w};
        #pragma unroll
        for (int i = 0; i < 4; ++i)
            #pragma unroll
            for (int j = 0; j < 4; ++j)
                acc[i][j] += a[i] * b[j];
    }
    #pragma unroll
    for (int i = 0; i < 4; ++i)
        #pragma unroll
        for (int j = 0; j < 4; ++j) {
            int g = (R0 + 4 * tx + i) * MI + C0 + 4 * ty + j;
            A[g] -= acc[i][j];
        }
}

// ---------------- invert 64x64 diagonal triangular blocks (8 wgs) -----------
__global__ void k_dinv(const float* __restrict__ LK, const float* __restrict__ LM,
                       float* __restrict__ LiK, float* __restrict__ LiM) {
    const float* L = blockIdx.y ? LM : LK;
    float* Li = blockIdx.y ? LiM : LiK;
    int o = 64 * blockIdx.x;
    __shared__ float Lb[64 * 64], X[64 * 64];
    int tid = threadIdx.x;
    int j = tid & 63, rg = tid >> 6;
    for (int q = tid; q < 4096; q += 256) {
        int rr = q >> 6, c = q & 63;
        Lb[q] = L[(o + rr) * MI + o + c];
        X[q] = (rr == c) ? 1.f : 0.f;
    }
    __syncthreads();
    for (int i = 0; i < 64; ++i) {
        if (tid < 64) X[i * 64 + tid] *= (1.0f / Lb[i * 64 + i]);
        __syncthreads();
        float xi = X[i * 64 + j];
        for (int rr = i + 1 + rg; rr < 64; rr += 4)
            X[rr * 64 + j] = fmaf(-Lb[rr * 64 + i], xi, X[rr * 64 + j]);
        __syncthreads();
    }
    for (int q = tid; q < 4096; q += 256) {
        int rr = q >> 6, c = q & 63;
        Li[(o + rr) * MI + o + c] = X[q];
    }
}

// ---- off-diagonal Linv blocks at distance d: X_ij = -Linv_ii * sum L_ik X_kj
__global__ void k_toff(const float* __restrict__ LAK, const float* __restrict__ LAM,
                       float* __restrict__ LiK, float* __restrict__ LiM, int d) {
    const float* LA = blockIdx.y ? LAM : LAK;
    float* Li = blockIdx.y ? LiM : LiK;
    int j = blockIdx.x, i = j + d;
    __shared__ float As[64 * 68], Bs[64 * 68];
    int tid = threadIdx.x;
    int tx = tid & 15, ty = tid >> 4;
    float acc[4][4] = {};
    for (int m = 0; m < d; ++m) {
        int kb = j + m;
        __syncthreads();
        for (int q = tid; q < 4096; q += 256) {
            int rr = q >> 6, k = q & 63;
            As[k * 68 + rr] = LA[(64 * i + rr) * MI + 64 * kb + k];
        }
        for (int q = tid; q < 4096; q += 256) {
            int k = q >> 6, c = q & 63;
            Bs[k * 68 + c] = Li[(64 * kb + k) * MI + 64 * j + c];
        }
        __syncthreads();
        #pragma unroll 4
        for (int k = 0; k < 64; ++k) {
            float4 a4 = *(const float4*)&As[k * 68 + 4 * tx];
            float4 b4 = *(const float4*)&Bs[k * 68 + 4 * ty];
            float a[4] = {a4.x, a4.y, a4.z, a4.w};
            float b[4] = {b4.x, b4.y, b4.z, b4.w};
            #pragma unroll
            for (int i2 = 0; i2 < 4; ++i2)
                #pragma unroll
                for (int j2 = 0; j2 < 4; ++j2)
                    acc[i2][j2] += a[i2] * b[j2];
        }
    }
    __syncthreads();
    // stage T into Bs (row-major), Linv_ii (transposed) into As
    #pragma unroll
    for (int i2 = 0; i2 < 4; ++i2)
        #pragma unroll
        for (int j2 = 0; j2 < 4; ++j2)
            Bs[(4 * tx + i2) * 68 + 4 * ty + j2] = acc[i2][j2];
    for (int q = tid; q < 4096; q += 256) {
        int rr = q >> 6, k = q & 63;
        As[k * 68 + rr] = Li[(64 * i + rr) * MI + 64 * i + k];
    }
    __syncthreads();
    float out[4][4] = {};
    #pragma unroll 4
    for (int k = 0; k < 64; ++k) {
        float4 a4 = *(const float4*)&As[k * 68 + 4 * tx];
        float4 b4 = *(const float4*)&Bs[k * 68 + 4 * ty];
        float a[4] = {a4.x, a4.y, a4.z, a4.w};
        float b[4] = {b4.x, b4.y, b4.z, b4.w};
        #pragma unroll
        for (int i2 = 0; i2 < 4; ++i2)
            #pragma unroll
            for (int j2 = 0; j2 < 4; ++j2)
                out[i2][j2] += a[i2] * b[j2];
    }
    #pragma unroll
    for (int i2 = 0; i2 < 4; ++i2)
        #pragma unroll
        for (int j2 = 0; j2 < 4; ++j2)
            Li[(64 * i + 4 * tx + i2) * MI + 64 * j + 4 * ty + j2] = -out[i2][j2];
}

// -------- trace(AAT)*sigma2 = <LinvK*S, LinvK>  (16 tiles, fused dot) -------
__global__ void k_trace(const float* __restrict__ Li, const float* __restrict__ S,
                        float* __restrict__ acc) {
    __shared__ __align__(16) float As[16 * 68], Bs[16 * 68];
    __shared__ float red[256];
    int tid = threadIdx.x;
    int R = 64 * (blockIdx.x >> 2), C = 64 * (blockIdx.x & 3);
    int tx = tid & 15, ty = tid >> 4;
    float acc4[4][4] = {};
    for (int k0 = 0; k0 < MI; k0 += 16) {
        __syncthreads();
        for (int q = tid; q < 1024; q += 256) {
            int rr = q >> 4, kk = q & 15;
            As[kk * 68 + rr] = Li[(R + rr) * MI + k0 + kk];
        }
        for (int q = tid; q < 1024; q += 256) {
            int kk = q >> 6, c = q & 63;
            Bs[kk * 68 + c] = S[(k0 + kk) * MI + C + c];
        }
        __syncthreads();
        #pragma unroll
        for (int k = 0; k < 16; ++k) {
            float4 a4 = *(const float4*)&As[k * 68 + 4 * tx];
            float4 b4 = *(const float4*)&Bs[k * 68 + 4 * ty];
            float a[4] = {a4.x, a4.y, a4.z, a4.w};
            float b[4] = {b4.x, b4.y, b4.z, b4.w};
            #pragma unroll
            for (int i = 0; i < 4; ++i)
                #pragma unroll
                for (int j = 0; j < 4; ++j)
                    acc4[i][j] += a[i] * b[j];
        }
    }
    float ts = 0.f;
    #pragma unroll
    for (int i = 0; i < 4; ++i)
        #pragma unroll
        for (int j = 0; j < 4; ++j)
            ts += acc4[i][j] * Li[(R + 4 * tx + i) * MI + C + 4 * ty + j];
    red[tid] = ts;
    __syncthreads();
    for (int st = 128; st > 0; st >>= 1) {
        if (tid < st) red[tid] += red[tid + st];
        __syncthreads();
    }
    if (tid == 0) atomicAdd(&acc[1], red[0]);
}

// -------- w = LinvM*G ; assemble bound ----------
__global__ void k_final(const float* __restrict__ LiM, const float* __restrict__ G,
                        const float* __restrict__ accbuf, const float* __restrict__ kvp,
                        float* __restrict__ out) {
    __shared__ float Gs[MI * DOUT];
    __shared__ float red[256];
    int tid = threadIdx.x;
    for (int i = tid; i < MI * DOUT; i += 256) Gs[i] = G[i];
    __syncthreads();
    float w[DOUT] = {};
    const float4* lrow4 = (const float4*)(LiM + tid * MI);
    for (int k4 = 0; k4 < MI / 4; ++k4) {
        float4 l = lrow4[k4];
        const float* g0 = &Gs[(4 * k4) * DOUT];
        #pragma unroll
        for (int d = 0; d < DOUT; ++d)
            w[d] += l.x * g0[d] + l.y * g0[DOUT + d] + l.z * g0[2 * DOUT + d] + l.w * g0[3 * DOUT + d];
    }
    float c2 = 0.f;
    #pragma unroll
    for (int d = 0; d < DOUT; ++d) c2 += w[d] * w[d];
    red[tid] = c2;
    __syncthreads();
    for (int st = 128; st > 0; st >>= 1) {
        if (tid < st) red[tid] += red[tid + st];
        __syncthreads();
    }
    if (tid == 0) {
        float kv = kvp[0];
        float trace = accbuf[1] * INV_SIGMA2;              // trace(AAT)
        float logdetB = accbuf[3] - accbuf[2];             // logdet(M2)-logdet(Kuu)
        float bound = -0.5f * (float)(NH * DOUT) * __logf(6.28318530717959f * SIGMA2)
                      - 0.5f * INV_SIGMA2 * accbuf[0]
                      - 0.5f * (float)DOUT * ((float)NH * kv * INV_SIGMA2 - trace)
                      - 0.5f * (float)DOUT * logdetB
                      + 0.5f * 1.0e6f * red[0];            // ||c||^2 = ||LinvM G||^2/sigma^4
        out[0] = bound;
    }
}

extern "C" void kernel_launch(void* const* d_in, const int* in_sizes, int n_in,
                              void* d_out, int out_size, void* d_ws, size_t ws_size,
                              hipStream_t stream) {
    (void)in_sizes; (void)n_in; (void)out_size; (void)ws_size;
    const float* Xm_m = (const float*)d_in[0];
    const float* Xm_v = (const float*)d_in[1];
    const float* Z    = (const float*)d_in[2];
    const float* Y    = (const float*)d_in[3];
    const float* kvp  = (const float*)d_in[4];
    const float* ls   = (const float*)d_in[5];
    float* out = (float*)d_out;
    float* W = (float*)d_ws;

    float* acc   = W;              // 16: [0]=sumY2 [1]=<LinvK S,LinvK> [2]=ldK [3]=ldM
    float* G     = W + 16;         // 4096
    float* LinvK = W + 4112;       // 65536
    float* LinvM = W + 69648;      // 65536   (zero range ends at 135184)
    float* vbar  = W + 135184;     // 80
    float* psi1  = W + 135264;     // 512000
    float* Eg    = W + 647264;     // 512000
    float* Kuu   = W + 1159264;    // 65536 (factored in place -> L_K)
    float* M2    = W + 1224800;    // 65536 (factored in place -> L_M)
    float* S     = W + 1290336;    // 65536 (psi2)
    float* F     = W + 1355872;    // 65536
    float* Spart = W + 1421408;    // 5*65536 (end ~7.0 MB)

    k_zero<<<529, 256, 0, stream>>>(W, 135184);            // acc, G, LinvK, LinvM
    k_prep<<<1, 256, 0, stream>>>(Xm_v, Y, ls, vbar, acc);
    k_main<<<NH, 256, 0, stream>>>(Xm_m, Xm_v, Z, ls, kvp, psi1, Eg);
    k_kuuF<<<MI, 256, 0, stream>>>(Z, ls, vbar, kvp, Kuu, F);
    k_syrk<<<dim3(16, 5), 256, 0, stream>>>(Eg, Spart);
    k_psi2M<<<MI, 256, 0, stream>>>(F, Spart, Kuu, S, M2);
    k_G<<<16, 256, 0, stream>>>(psi1, Y, G);

    // batched blocked Cholesky of {Kuu, M2}
    for (int p = 0; p < 4; ++p) {
        k_cholp<<<2, 512, 0, stream>>>(Kuu, M2, acc, p);
        if (p < 3) {
            int nt = 3 - p;
            k_cholu<<<dim3(nt * (nt + 1) / 2, 2), 256, 0, stream>>>(Kuu, M2, p);
        }
    }
    // batched blocked triangular inverse
    k_dinv<<<dim3(4, 2), 256, 0, stream>>>(Kuu, M2, LinvK, LinvM);
    for (int d = 1; d < 4; ++d)
        k_toff<<<dim3(4 - d, 2), 256, 0, stream>>>(Kuu, M2, LinvK, LinvM, d);

    k_trace<<<16, 256, 0, stream>>>(LinvK, S, acc);
    k_final<<<1, 256, 0, stream>>>(LinvM, G, acc, kvp, out);
}

// Round 6
// 691.300 us; speedup vs baseline: 3.0836x; 1.2280x over previous
//
#include <hip/hip_runtime.h>
#include <math.h>

// Problem constants (from setup_inputs: N_data=2000, Lt=10, Q=8, M=256, D=16)
#define NH   2000     // Hankel rows == Y rows
#define QD   8        // latent dim Q
#define DIN  80       // Lt*Q
#define MI   256      // inducing points
#define DOUT 16       // output dim D
#define SIGMA2     1e-3f
#define INV_SIGMA2 1000.0f
#define JITTER     1e-4f

// HARD-WON NOTES (rounds 1-5):
//  - per-thread arrays indexed dynamically -> scratch (4 ms).
//  - even static-indexed 64-float/thread tiles across barriered loops get
//    spilled by the allocator regardless of __launch_bounds__ /
//    amdgpu_waves_per_eu. Monolithic register-tiled 256x256 factorizations
//    are a dead end on gfx950 -> blocked LDS-resident panels (r5: 2131->849).
//  - single-workgroup kernels with long per-thread serial load loops are
//    latency chains (r5: k_prep 225 us for 96 KB of reads). Parallelize.

// ---------------- zero acc + G + LinvK + LinvM ----------------
__global__ void k_zero(float* __restrict__ W, int n) {
    int i = blockIdx.x * 256 + threadIdx.x;
    if (i < n) W[i] = 0.f;
}

// ---------------- vbar[j] (blocks 0..79) + sum(Y^2) (blocks 80..87) --------
__global__ void k_prep(const float* __restrict__ Xm_v, const float* __restrict__ Y,
                       const float* __restrict__ ls, float* __restrict__ vbar,
                       float* __restrict__ acc) {
    __shared__ float red[256];
    int tid = threadIdx.x;
    int b = blockIdx.x;
    if (b < DIN) {
        int j = b;
        int l = j >> 3, qq = j & 7;
        float lsv = ls[j];
        float ls2 = lsv * lsv;
        float s = 0.f;
        for (int n = tid; n < NH; n += 256) {
            float xv = Xm_v[(1 + n + l) * QD + qq];
            s += 1.0f / (2.0f * xv + ls2);
        }
        red[tid] = s;
        __syncthreads();
        for (int st = 128; st > 0; st >>= 1) {
            if (tid < st) red[tid] += red[tid + st];
            __syncthreads();
        }
        if (tid == 0) vbar[j] = red[0] * (1.0f / NH);
    } else {
        // 8 blocks x 256 threads over 8000 float4s of Y
        const float4* y4 = (const float4*)Y;
        float sy = 0.f;
        for (int i = (b - DIN) * 256 + tid; i < NH * DOUT / 4; i += 8 * 256) {
            float4 y = y4[i];
            sy += y.x * y.x + y.y * y.y + y.z * y.z + y.w * y.w;
        }
        red[tid] = sy;
        __syncthreads();
        for (int st = 128; st > 0; st >>= 1) {
            if (tid < st) red[tid] += red[tid + st];
            __syncthreads();
        }
        if (tid == 0) atomicAdd(&acc[0], red[0]);
    }
}

// ---------------- psi1[n,a] and Eg[n,a] (one block per n) ----------------
__global__ void k_main(const float* __restrict__ Xm_m, const float* __restrict__ Xm_v,
                       const float* __restrict__ Z, const float* __restrict__ ls,
                       const float* __restrict__ kvp,
                       float* __restrict__ psi1, float* __restrict__ Eg) {
    __shared__ __align__(16) float xm[DIN], h1[DIN], v2[DIN];
    __shared__ float red1[DIN], red2[DIN];
    __shared__ float sc[2];
    int tid = threadIdx.x;
    int n = blockIdx.x;
    if (tid < DIN) {
        int j = tid;
        int l = j >> 3, qq = j & 7;
        int row = 1 + n + l;                       // hankel(v[1:], Lt)
        float xmv = Xm_m[row * QD + qq];
        float xvv = Xm_v[row * QD + qq];
        float lsv = ls[j];
        float ls2 = lsv * lsv;
        float iv1 = 1.0f / (xvv + ls2);
        float iv2 = 1.0f / (2.0f * xvv + ls2);
        xm[j] = xmv; h1[j] = 0.5f * iv1; v2[j] = iv2;
        red1[j] = 0.5f * __logf(ls2 * iv1);                            // logc1 part
        red2[j] = 0.25f * __logf(ls2 * iv2) - 0.5f * xmv * xmv * iv2;  // 0.5*(logc2-base2)
    }
    __syncthreads();
    if (tid == 0) {
        float a = 0.f, b = 0.f;
        for (int j = 0; j < DIN; ++j) { a += red1[j]; b += red2[j]; }
        sc[0] = a; sc[1] = b;
    }
    __syncthreads();
    float c1 = sc[0], c2h = sc[1];
    const float4* zr  = (const float4*)(Z + tid * DIN);
    const float4* xm4 = (const float4*)xm;
    const float4* h14 = (const float4*)h1;
    const float4* v24 = (const float4*)v2;
    float e1h = 0.f, P = 0.f;
    #pragma unroll 4
    for (int j4 = 0; j4 < DIN / 4; ++j4) {
        float4 z = zr[j4], x = xm4[j4], h = h14[j4], v = v24[j4];
        float d;
        d = z.x - x.x; e1h += h.x * d * d; P += v.x * z.x * (0.25f * z.x - x.x);
        d = z.y - x.y; e1h += h.y * d * d; P += v.y * z.y * (0.25f * z.y - x.y);
        d = z.z - x.z; e1h += h.z * d * d; P += v.z * z.z * (0.25f * z.z - x.z);
        d = z.w - x.w; e1h += h.w * d * d; P += v.w * z.w * (0.25f * z.w - x.w);
    }
    float kv = kvp[0];
    psi1[n * MI + tid] = kv * __expf(c1 - e1h);
    Eg [n * MI + tid] = __expf(c2h - P);
}

// ---------------- Kuu and F = kv^2*exp(-0.25*d2 - 0.5*C0) ----------------
__global__ void k_kuuF(const float* __restrict__ Z, const float* __restrict__ ls,
                       const float* __restrict__ vbar, const float* __restrict__ kvp,
                       float* __restrict__ Kuu, float* __restrict__ F) {
    __shared__ __align__(16) float ils2[DIN];
    int tid = threadIdx.x;
    int b = blockIdx.x;
    if (tid < DIN) { float l = ls[tid]; ils2[tid] = 1.0f / (l * l); }
    __syncthreads();
    const float4* za4 = (const float4*)(Z + tid * DIN);
    const float4* zb4 = (const float4*)(Z + b * DIN);
    const float4* il4 = (const float4*)ils2;
    const float4* vb4 = (const float4*)vbar;
    float d2a = 0.f, c0 = 0.f;
    #pragma unroll 4
    for (int j4 = 0; j4 < DIN / 4; ++j4) {
        float4 za = za4[j4], zb = zb4[j4], il = il4[j4], vb = vb4[j4];
        float d;
        d = za.x - zb.x; d2a += d * d * il.x; c0 += vb.x * za.x * zb.x;
        d = za.y - zb.y; d2a += d * d * il.y; c0 += vb.y * za.y * zb.y;
        d = za.z - zb.z; d2a += d * d * il.z; c0 += vb.z * za.z * zb.z;
        d = za.w - zb.w; d2a += d * d * il.w; c0 += vb.w * za.w * zb.w;
    }
    float kv = kvp[0];
    int a = tid;
    Kuu[b * MI + a] = kv * __expf(-0.5f * d2a) + (a == b ? JITTER : 0.f);
    F  [b * MI + a] = kv * kv * __expf(-0.25f * d2a - 0.5f * c0);
}

// ---------------- S_part[y] = partial Eg^T Eg (64x64 tiles, split-K=5) ------
__global__ void k_syrk(const float* __restrict__ Eg, float* __restrict__ Spart) {
    __shared__ __align__(16) float As[16 * 64], Bs[16 * 64];
    int tid = threadIdx.x;
    int ta = blockIdx.x & 3, tb = blockIdx.x >> 2;
    int k0 = blockIdx.y * 400;
    int tx = tid & 15, ty = tid >> 4;
    float acc[4][4] = {};
    for (int kk = k0; kk < k0 + 400; kk += 16) {
        __syncthreads();
        for (int i = tid; i < 1024; i += 256) {
            int k = i >> 6, c = i & 63;
            As[k * 64 + c] = Eg[(kk + k) * MI + 64 * ta + c];
            Bs[k * 64 + c] = Eg[(kk + k) * MI + 64 * tb + c];
        }
        __syncthreads();
        #pragma unroll
        for (int k = 0; k < 16; ++k) {
            float4 a4 = *(const float4*)&As[k * 64 + 4 * tx];
            float4 b4 = *(const float4*)&Bs[k * 64 + 4 * ty];
            float a[4] = {a4.x, a4.y, a4.z, a4.w};
            float b[4] = {b4.x, b4.y, b4.z, b4.w};
            #pragma unroll
            for (int i = 0; i < 4; ++i)
                #pragma unroll
                for (int j = 0; j < 4; ++j)
                    acc[i][j] += a[i] * b[j];
        }
    }
    float* out = Spart + blockIdx.y * (MI * MI);
    #pragma unroll
    for (int i = 0; i < 4; ++i)
        #pragma unroll
        for (int j = 0; j < 4; ++j)
            out[(64 * ta + 4 * tx + i) * MI + 64 * tb + 4 * ty + j] = acc[i][j];
}

// ---------------- S(=psi2) = F * sum_y Spart ; M2 = Kuu + S/sigma2 ----------
__global__ void k_psi2M(const float* __restrict__ F, const float* __restrict__ Spart,
                        const float* __restrict__ Kuu,
                        float* __restrict__ S, float* __restrict__ M2) {
    int i = blockIdx.x * 256 + threadIdx.x;
    float s = Spart[i] + Spart[MI * MI + i] + Spart[2 * MI * MI + i]
            + Spart[3 * MI * MI + i] + Spart[4 * MI * MI + i];
    float v = F[i] * s;
    S[i] = v;
    M2[i] = Kuu[i] + INV_SIGMA2 * v;
}

// ---------------- G += psi1^T Y ----------------
__global__ void k_G(const float* __restrict__ psi1, const float* __restrict__ Y,
                    float* __restrict__ G) {
    int a = threadIdx.x;
    int n0 = blockIdx.x * 125;
    float acc[DOUT] = {};
    for (int n = n0; n < n0 + 125; ++n) {
        float p = psi1[n * MI + a];
        #pragma unroll
        for (int d = 0; d < DOUT; ++d) acc[d] += p * Y[n * DOUT + d];
    }
    #pragma unroll
    for (int d = 0; d < DOUT; ++d) atomicAdd(&G[a * DOUT + d], acc[d]);
}

// ---------------- panel Cholesky (cols [64p,64p+64), rows [64p,256)) --------
// LDS-resident, column-major P[c*H+r]; batched over {Kuu, M2} via blockIdx.x.
__global__ void k_cholp(float* __restrict__ AK, float* __restrict__ AM,
                        float* __restrict__ acc, int p) {
    float* A = blockIdx.x ? AM : AK;
    const int c0 = 64 * p, H = 256 - c0;
    __shared__ float P[64 * 256];            // 64 KB max (p=0)
    int tid = threadIdx.x;                   // 512 threads
    int r = tid >> 1, h = tid & 1;
    if (r < H) {
        const float* arow = A + (c0 + r) * MI + c0;
        for (int c = 32 * h; c < 32 * h + 32; ++c) P[c * H + r] = arow[c];
    }
    __syncthreads();
    float lgsum = 0.f;
    for (int kk = 0; kk < 64; ++kk) {
        float piv = P[kk * H + kk];          // final since prev iter's barrier
        float is = rsqrtf(piv);
        if (tid == 0) { lgsum += __logf(piv); A[(c0 + kk) * MI + c0 + kk] = piv * is; }
        if (h == 0 && r > kk && r < H) P[kk * H + r] *= is;  // scale col kk (r>kk only)
        __syncthreads();
        if (r > kk && r < H) {
            float m = P[kk * H + r];
            for (int c = kk + 1 + h; c < 64; c += 2)
                P[c * H + r] = fmaf(-m, P[kk * H + c], P[c * H + r]);
        }
        __syncthreads();
    }
    if (r < H) {
        for (int c = 32 * h; c < 32 * h + 32; ++c)
            if (r > c) A[(c0 + r) * MI + c0 + c] = P[c * H + r];
    }
    if (tid == 0) atomicAdd(&acc[2 + blockIdx.x], lgsum);
}

// ---------------- trailing update: A22 -= Lp * Lp^T (64x64x64 tiles) --------
__global__ void k_cholu(float* __restrict__ AK, float* __restrict__ AM, int p) {
    float* A = blockIdx.y ? AM : AK;
    int t0 = 64 * (p + 1);
    int idx = blockIdx.x, ti = 0;
    while (idx > ti) { idx -= ti + 1; ti++; }
    int tj = idx;                            // lower tiles ti >= tj
    int R0 = t0 + 64 * ti, C0 = t0 + 64 * tj, K0 = 64 * p;
    __shared__ float As[64 * 68], Bs[64 * 68];
    int tid = threadIdx.x;
    int tx = tid & 15, ty = tid >> 4;
    for (int q = tid; q < 4096; q += 256) {
        int rr = q >> 6, k = q & 63;
        As[k * 68 + rr] = A[(R0 + rr) * MI + K0 + k];
        Bs[k * 68 + rr] = A[(C0 + rr) * MI + K0 + k];
    }
    __syncthreads();
    float acc[4][4] = {};
    #pragma unroll 4
    for (int k = 0; k < 64; ++k) {
        float4 a4 = *(const float4*)&As[k * 68 + 4 * tx];
        float4 b4 = *(const float4*)&Bs[k * 68 + 4 * ty];
        float a[4] = {a4.x, a4.y, a4.z, a4.w};
        float b[4] = {b4.x, b4.y, b4.z, b4.w};
        #pragma unroll
        for (int i = 0; i < 4; ++i)
            #pragma unroll
            for (int j = 0; j < 4; ++j)
                acc[i][j] += a[i] * b[j];
    }
    #pragma unroll
    for (int i = 0; i < 4; ++i)
        #pragma unroll
        for (int j = 0; j < 4; ++j) {
            int g = (R0 + 4 * tx + i) * MI + C0 + 4 * ty + j;
            A[g] -= acc[i][j];
        }
}

// ---------------- invert 64x64 diagonal triangular blocks (8 wgs) -----------
__global__ void k_dinv(const float* __restrict__ LK, const float* __restrict__ LM,
                       float* __restrict__ LiK, float* __restrict__ LiM) {
    const float* L = blockIdx.y ? LM : LK;
    float* Li = blockIdx.y ? LiM : LiK;
    int o = 64 * blockIdx.x;
    __shared__ float Lb[64 * 64], X[64 * 64];
    int tid = threadIdx.x;
    int j = tid & 63, rg = tid >> 6;
    for (int q = tid; q < 4096; q += 256) {
        int rr = q >> 6, c = q & 63;
        Lb[q] = L[(o + rr) * MI + o + c];
        X[q] = (rr == c) ? 1.f : 0.f;
    }
    __syncthreads();
    for (int i = 0; i < 64; ++i) {
        if (tid < 64) X[i * 64 + tid] *= (1.0f / Lb[i * 64 + i]);
        __syncthreads();
        float xi = X[i * 64 + j];
        for (int rr = i + 1 + rg; rr < 64; rr += 4)
            X[rr * 64 + j] = fmaf(-Lb[rr * 64 + i], xi, X[rr * 64 + j]);
        __syncthreads();
    }
    for (int q = tid; q < 4096; q += 256) {
        int rr = q >> 6, c = q & 63;
        Li[(o + rr) * MI + o + c] = X[q];
    }
}

// ---- off-diagonal Linv blocks at distance d: X_ij = -Linv_ii * sum L_ik X_kj
__global__ void k_toff(const float* __restrict__ LAK, const float* __restrict__ LAM,
                       float* __restrict__ LiK, float* __restrict__ LiM, int d) {
    const float* LA = blockIdx.y ? LAM : LAK;
    float* Li = blockIdx.y ? LiM : LiK;
    int j = blockIdx.x, i = j + d;
    __shared__ float As[64 * 68], Bs[64 * 68];
    int tid = threadIdx.x;
    int tx = tid & 15, ty = tid >> 4;
    float acc[4][4] = {};
    for (int m = 0; m < d; ++m) {
        int kb = j + m;
        __syncthreads();
        for (int q = tid; q < 4096; q += 256) {
            int rr = q >> 6, k = q & 63;
            As[k * 68 + rr] = LA[(64 * i + rr) * MI + 64 * kb + k];
        }
        for (int q = tid; q < 4096; q += 256) {
            int k = q >> 6, c = q & 63;
            Bs[k * 68 + c] = Li[(64 * kb + k) * MI + 64 * j + c];
        }
        __syncthreads();
        #pragma unroll 4
        for (int k = 0; k < 64; ++k) {
            float4 a4 = *(const float4*)&As[k * 68 + 4 * tx];
            float4 b4 = *(const float4*)&Bs[k * 68 + 4 * ty];
            float a[4] = {a4.x, a4.y, a4.z, a4.w};
            float b[4] = {b4.x, b4.y, b4.z, b4.w};
            #pragma unroll
            for (int i2 = 0; i2 < 4; ++i2)
                #pragma unroll
                for (int j2 = 0; j2 < 4; ++j2)
                    acc[i2][j2] += a[i2] * b[j2];
        }
    }
    __syncthreads();
    // stage T into Bs (row-major), Linv_ii (transposed) into As
    #pragma unroll
    for (int i2 = 0; i2 < 4; ++i2)
        #pragma unroll
        for (int j2 = 0; j2 < 4; ++j2)
            Bs[(4 * tx + i2) * 68 + 4 * ty + j2] = acc[i2][j2];
    for (int q = tid; q < 4096; q += 256) {
        int rr = q >> 6, k = q & 63;
        As[k * 68 + rr] = Li[(64 * i + rr) * MI + 64 * i + k];
    }
    __syncthreads();
    float out[4][4] = {};
    #pragma unroll 4
    for (int k = 0; k < 64; ++k) {
        float4 a4 = *(const float4*)&As[k * 68 + 4 * tx];
        float4 b4 = *(const float4*)&Bs[k * 68 + 4 * ty];
        float a[4] = {a4.x, a4.y, a4.z, a4.w};
        float b[4] = {b4.x, b4.y, b4.z, b4.w};
        #pragma unroll
        for (int i2 = 0; i2 < 4; ++i2)
            #pragma unroll
            for (int j2 = 0; j2 < 4; ++j2)
                out[i2][j2] += a[i2] * b[j2];
    }
    #pragma unroll
    for (int i2 = 0; i2 < 4; ++i2)
        #pragma unroll
        for (int j2 = 0; j2 < 4; ++j2)
            Li[(64 * i + 4 * tx + i2) * MI + 64 * j + 4 * ty + j2] = -out[i2][j2];
}

// -------- trace(AAT)*sigma2 = <LinvK*S, LinvK>  (16 tiles, fused dot) -------
__global__ void k_trace(const float* __restrict__ Li, const float* __restrict__ S,
                        float* __restrict__ acc) {
    __shared__ __align__(16) float As[16 * 68], Bs[16 * 68];
    __shared__ float red[256];
    int tid = threadIdx.x;
    int R = 64 * (blockIdx.x >> 2), C = 64 * (blockIdx.x & 3);
    int tx = tid & 15, ty = tid >> 4;
    float acc4[4][4] = {};
    for (int k0 = 0; k0 < MI; k0 += 16) {
        __syncthreads();
        for (int q = tid; q < 1024; q += 256) {
            int rr = q >> 4, kk = q & 15;
            As[kk * 68 + rr] = Li[(R + rr) * MI + k0 + kk];
        }
        for (int q = tid; q < 1024; q += 256) {
            int kk = q >> 6, c = q & 63;
            Bs[kk * 68 + c] = S[(k0 + kk) * MI + C + c];
        }
        __syncthreads();
        #pragma unroll
        for (int k = 0; k < 16; ++k) {
            float4 a4 = *(const float4*)&As[k * 68 + 4 * tx];
            float4 b4 = *(const float4*)&Bs[k * 68 + 4 * ty];
            float a[4] = {a4.x, a4.y, a4.z, a4.w};
            float b[4] = {b4.x, b4.y, b4.z, b4.w};
            #pragma unroll
            for (int i = 0; i < 4; ++i)
                #pragma unroll
                for (int j = 0; j < 4; ++j)
                    acc4[i][j] += a[i] * b[j];
        }
    }
    float ts = 0.f;
    #pragma unroll
    for (int i = 0; i < 4; ++i)
        #pragma unroll
        for (int j = 0; j < 4; ++j)
            ts += acc4[i][j] * Li[(R + 4 * tx + i) * MI + C + 4 * ty + j];
    red[tid] = ts;
    __syncthreads();
    for (int st = 128; st > 0; st >>= 1) {
        if (tid < st) red[tid] += red[tid + st];
        __syncthreads();
    }
    if (tid == 0) atomicAdd(&acc[1], red[0]);
}

// -------- w = LinvM*G ; assemble bound ----------
__global__ void k_final(const float* __restrict__ LiM, const float* __restrict__ G,
                        const float* __restrict__ accbuf, const float* __restrict__ kvp,
                        float* __restrict__ out) {
    __shared__ float Gs[MI * DOUT];
    __shared__ float red[256];
    int tid = threadIdx.x;
    for (int i = tid; i < MI * DOUT; i += 256) Gs[i] = G[i];
    __syncthreads();
    float w[DOUT] = {};
    const float4* lrow4 = (const float4*)(LiM + tid * MI);
    for (int k4 = 0; k4 < MI / 4; ++k4) {
        float4 l = lrow4[k4];
        const float* g0 = &Gs[(4 * k4) * DOUT];
        #pragma unroll
        for (int d = 0; d < DOUT; ++d)
            w[d] += l.x * g0[d] + l.y * g0[DOUT + d] + l.z * g0[2 * DOUT + d] + l.w * g0[3 * DOUT + d];
    }
    float c2 = 0.f;
    #pragma unroll
    for (int d = 0; d < DOUT; ++d) c2 += w[d] * w[d];
    red[tid] = c2;
    __syncthreads();
    for (int st = 128; st > 0; st >>= 1) {
        if (tid < st) red[tid] += red[tid + st];
        __syncthreads();
    }
    if (tid == 0) {
        float kv = kvp[0];
        float trace = accbuf[1] * INV_SIGMA2;              // trace(AAT)
        float logdetB = accbuf[3] - accbuf[2];             // logdet(M2)-logdet(Kuu)
        float bound = -0.5f * (float)(NH * DOUT) * __logf(6.28318530717959f * SIGMA2)
                      - 0.5f * INV_SIGMA2 * accbuf[0]
                      - 0.5f * (float)DOUT * ((float)NH * kv * INV_SIGMA2 - trace)
                      - 0.5f * (float)DOUT * logdetB
                      + 0.5f * 1.0e6f * red[0];            // ||c||^2 = ||LinvM G||^2/sigma^4
        out[0] = bound;
    }
}

extern "C" void kernel_launch(void* const* d_in, const int* in_sizes, int n_in,
                              void* d_out, int out_size, void* d_ws, size_t ws_size,
                              hipStream_t stream) {
    (void)in_sizes; (void)n_in; (void)out_size; (void)ws_size;
    const float* Xm_m = (const float*)d_in[0];
    const float* Xm_v = (const float*)d_in[1];
    const float* Z    = (const float*)d_in[2];
    const float* Y    = (const float*)d_in[3];
    const float* kvp  = (const float*)d_in[4];
    const float* ls   = (const float*)d_in[5];
    float* out = (float*)d_out;
    float* W = (float*)d_ws;

    float* acc   = W;              // 16: [0]=sumY2 [1]=<LinvK S,LinvK> [2]=ldK [3]=ldM
    float* G     = W + 16;         // 4096
    float* LinvK = W + 4112;       // 65536
    float* LinvM = W + 69648;      // 65536   (zero range ends at 135184)
    float* vbar  = W + 135184;     // 80
    float* psi1  = W + 135264;     // 512000
    float* Eg    = W + 647264;     // 512000
    float* Kuu   = W + 1159264;    // 65536 (factored in place -> L_K)
    float* M2    = W + 1224800;    // 65536 (factored in place -> L_M)
    float* S     = W + 1290336;    // 65536 (psi2)
    float* F     = W + 1355872;    // 65536
    float* Spart = W + 1421408;    // 5*65536 (end ~7.0 MB)

    k_zero<<<529, 256, 0, stream>>>(W, 135184);            // acc, G, LinvK, LinvM
    k_prep<<<DIN + 8, 256, 0, stream>>>(Xm_v, Y, ls, vbar, acc);
    k_main<<<NH, 256, 0, stream>>>(Xm_m, Xm_v, Z, ls, kvp, psi1, Eg);
    k_kuuF<<<MI, 256, 0, stream>>>(Z, ls, vbar, kvp, Kuu, F);
    k_syrk<<<dim3(16, 5), 256, 0, stream>>>(Eg, Spart);
    k_psi2M<<<MI, 256, 0, stream>>>(F, Spart, Kuu, S, M2);
    k_G<<<16, 256, 0, stream>>>(psi1, Y, G);

    // batched blocked Cholesky of {Kuu, M2}
    for (int p = 0; p < 4; ++p) {
        k_cholp<<<2, 512, 0, stream>>>(Kuu, M2, acc, p);
        if (p < 3) {
            int nt = 3 - p;
            k_cholu<<<dim3(nt * (nt + 1) / 2, 2), 256, 0, stream>>>(Kuu, M2, p);
        }
    }
    // batched blocked triangular inverse
    k_dinv<<<dim3(4, 2), 256, 0, stream>>>(Kuu, M2, LinvK, LinvM);
    for (int d = 1; d < 4; ++d)
        k_toff<<<dim3(4 - d, 2), 256, 0, stream>>>(Kuu, M2, LinvK, LinvM, d);

    k_trace<<<16, 256, 0, stream>>>(LinvK, S, acc);
    k_final<<<1, 256, 0, stream>>>(LinvM, G, acc, kvp, out);
}

// Round 7
// 606.447 us; speedup vs baseline: 3.5150x; 1.1399x over previous
//
#include <hip/hip_runtime.h>
#include <math.h>

// Problem constants (from setup_inputs: N_data=2000, Lt=10, Q=8, M=256, D=16)
#define NH   2000     // Hankel rows == Y rows
#define QD   8        // latent dim Q
#define DIN  80       // Lt*Q
#define MI   256      // inducing points
#define DOUT 16       // output dim D
#define SIGMA2     1e-3f
#define INV_SIGMA2 1000.0f
#define JITTER     1e-4f

// HARD-WON NOTES (rounds 1-6):
//  - per-thread arrays indexed dynamically -> scratch (4 ms).
//  - 64-float/thread register tiles across barriered loops get spilled by the
//    allocator no matter what launch bounds say; 16-float (4x4) tiles are fine
//    (k_syrk/k_cholu hold them without spilling).
//  - single-workgroup kernels with long serial loops are latency chains:
//    k_prep (r5, 225 us), k_cholp full-panel pivots (r6, 4x86 us: 64 pivots x
//    2 x 8-wave barriers + LDS-b32 rank-1). Keep the serial part 64x64 and
//    register-tiled with 1 barrier/pivot; do everything else as parallel GEMMs.

// ---------------- zero acc + G + LinvK + LinvM ----------------
__global__ void k_zero(float* __restrict__ W, int n) {
    int i = blockIdx.x * 256 + threadIdx.x;
    if (i < n) W[i] = 0.f;
}

// ---------------- vbar[j] (blocks 0..79) + sum(Y^2) (blocks 80..87) --------
__global__ void k_prep(const float* __restrict__ Xm_v, const float* __restrict__ Y,
                       const float* __restrict__ ls, float* __restrict__ vbar,
                       float* __restrict__ acc) {
    __shared__ float red[256];
    int tid = threadIdx.x;
    int b = blockIdx.x;
    if (b < DIN) {
        int j = b;
        int l = j >> 3, qq = j & 7;
        float lsv = ls[j];
        float ls2 = lsv * lsv;
        float s = 0.f;
        for (int n = tid; n < NH; n += 256) {
            float xv = Xm_v[(1 + n + l) * QD + qq];
            s += 1.0f / (2.0f * xv + ls2);
        }
        red[tid] = s;
        __syncthreads();
        for (int st = 128; st > 0; st >>= 1) {
            if (tid < st) red[tid] += red[tid + st];
            __syncthreads();
        }
        if (tid == 0) vbar[j] = red[0] * (1.0f / NH);
    } else {
        const float4* y4 = (const float4*)Y;
        float sy = 0.f;
        for (int i = (b - DIN) * 256 + tid; i < NH * DOUT / 4; i += 8 * 256) {
            float4 y = y4[i];
            sy += y.x * y.x + y.y * y.y + y.z * y.z + y.w * y.w;
        }
        red[tid] = sy;
        __syncthreads();
        for (int st = 128; st > 0; st >>= 1) {
            if (tid < st) red[tid] += red[tid + st];
            __syncthreads();
        }
        if (tid == 0) atomicAdd(&acc[0], red[0]);
    }
}

// ---------------- psi1[n,a] and Eg[n,a] (one block per n) ----------------
__global__ void k_main(const float* __restrict__ Xm_m, const float* __restrict__ Xm_v,
                       const float* __restrict__ Z, const float* __restrict__ ls,
                       const float* __restrict__ kvp,
                       float* __restrict__ psi1, float* __restrict__ Eg) {
    __shared__ __align__(16) float xm[DIN], h1[DIN], v2[DIN];
    __shared__ float red1[DIN], red2[DIN];
    __shared__ float sc[2];
    int tid = threadIdx.x;
    int n = blockIdx.x;
    if (tid < DIN) {
        int j = tid;
        int l = j >> 3, qq = j & 7;
        int row = 1 + n + l;                       // hankel(v[1:], Lt)
        float xmv = Xm_m[row * QD + qq];
        float xvv = Xm_v[row * QD + qq];
        float lsv = ls[j];
        float ls2 = lsv * lsv;
        float iv1 = 1.0f / (xvv + ls2);
        float iv2 = 1.0f / (2.0f * xvv + ls2);
        xm[j] = xmv; h1[j] = 0.5f * iv1; v2[j] = iv2;
        red1[j] = 0.5f * __logf(ls2 * iv1);                            // logc1 part
        red2[j] = 0.25f * __logf(ls2 * iv2) - 0.5f * xmv * xmv * iv2;  // 0.5*(logc2-base2)
    }
    __syncthreads();
    if (tid == 0) {
        float a = 0.f, b = 0.f;
        for (int j = 0; j < DIN; ++j) { a += red1[j]; b += red2[j]; }
        sc[0] = a; sc[1] = b;
    }
    __syncthreads();
    float c1 = sc[0], c2h = sc[1];
    const float4* zr  = (const float4*)(Z + tid * DIN);
    const float4* xm4 = (const float4*)xm;
    const float4* h14 = (const float4*)h1;
    const float4* v24 = (const float4*)v2;
    float e1h = 0.f, P = 0.f;
    #pragma unroll 4
    for (int j4 = 0; j4 < DIN / 4; ++j4) {
        float4 z = zr[j4], x = xm4[j4], h = h14[j4], v = v24[j4];
        float d;
        d = z.x - x.x; e1h += h.x * d * d; P += v.x * z.x * (0.25f * z.x - x.x);
        d = z.y - x.y; e1h += h.y * d * d; P += v.y * z.y * (0.25f * z.y - x.y);
        d = z.z - x.z; e1h += h.z * d * d; P += v.z * z.z * (0.25f * z.z - x.z);
        d = z.w - x.w; e1h += h.w * d * d; P += v.w * z.w * (0.25f * z.w - x.w);
    }
    float kv = kvp[0];
    psi1[n * MI + tid] = kv * __expf(c1 - e1h);
    Eg [n * MI + tid] = __expf(c2h - P);
}

// ---------------- Kuu and F = kv^2*exp(-0.25*d2 - 0.5*C0) ----------------
__global__ void k_kuuF(const float* __restrict__ Z, const float* __restrict__ ls,
                       const float* __restrict__ vbar, const float* __restrict__ kvp,
                       float* __restrict__ Kuu, float* __restrict__ F) {
    __shared__ __align__(16) float ils2[DIN];
    int tid = threadIdx.x;
    int b = blockIdx.x;
    if (tid < DIN) { float l = ls[tid]; ils2[tid] = 1.0f / (l * l); }
    __syncthreads();
    const float4* za4 = (const float4*)(Z + tid * DIN);
    const float4* zb4 = (const float4*)(Z + b * DIN);
    const float4* il4 = (const float4*)ils2;
    const float4* vb4 = (const float4*)vbar;
    float d2a = 0.f, c0 = 0.f;
    #pragma unroll 4
    for (int j4 = 0; j4 < DIN / 4; ++j4) {
        float4 za = za4[j4], zb = zb4[j4], il = il4[j4], vb = vb4[j4];
        float d;
        d = za.x - zb.x; d2a += d * d * il.x; c0 += vb.x * za.x * zb.x;
        d = za.y - zb.y; d2a += d * d * il.y; c0 += vb.y * za.y * zb.y;
        d = za.z - zb.z; d2a += d * d * il.z; c0 += vb.z * za.z * zb.z;
        d = za.w - zb.w; d2a += d * d * il.w; c0 += vb.w * za.w * zb.w;
    }
    float kv = kvp[0];
    int a = tid;
    Kuu[b * MI + a] = kv * __expf(-0.5f * d2a) + (a == b ? JITTER : 0.f);
    F  [b * MI + a] = kv * kv * __expf(-0.25f * d2a - 0.5f * c0);
}

// ---------------- S_part[y] = partial Eg^T Eg (64x64 tiles, split-K=5) ------
__global__ void k_syrk(const float* __restrict__ Eg, float* __restrict__ Spart) {
    __shared__ __align__(16) float As[16 * 64], Bs[16 * 64];
    int tid = threadIdx.x;
    int ta = blockIdx.x & 3, tb = blockIdx.x >> 2;
    int k0 = blockIdx.y * 400;
    int tx = tid & 15, ty = tid >> 4;
    float acc[4][4] = {};
    for (int kk = k0; kk < k0 + 400; kk += 16) {
        __syncthreads();
        for (int i = tid; i < 1024; i += 256) {
            int k = i >> 6, c = i & 63;
            As[k * 64 + c] = Eg[(kk + k) * MI + 64 * ta + c];
            Bs[k * 64 + c] = Eg[(kk + k) * MI + 64 * tb + c];
        }
        __syncthreads();
        #pragma unroll
        for (int k = 0; k < 16; ++k) {
            float4 a4 = *(const float4*)&As[k * 64 + 4 * tx];
            float4 b4 = *(const float4*)&Bs[k * 64 + 4 * ty];
            float a[4] = {a4.x, a4.y, a4.z, a4.w};
            float b[4] = {b4.x, b4.y, b4.z, b4.w};
            #pragma unroll
            for (int i = 0; i < 4; ++i)
                #pragma unroll
                for (int j = 0; j < 4; ++j)
                    acc[i][j] += a[i] * b[j];
        }
    }
    float* out = Spart + blockIdx.y * (MI * MI);
    #pragma unroll
    for (int i = 0; i < 4; ++i)
        #pragma unroll
        for (int j = 0; j < 4; ++j)
            out[(64 * ta + 4 * tx + i) * MI + 64 * tb + 4 * ty + j] = acc[i][j];
}

// ---------------- S(=psi2) = F * sum_y Spart ; M2 = Kuu + S/sigma2 ----------
__global__ void k_psi2M(const float* __restrict__ F, const float* __restrict__ Spart,
                        const float* __restrict__ Kuu,
                        float* __restrict__ S, float* __restrict__ M2) {
    int i = blockIdx.x * 256 + threadIdx.x;
    float s = Spart[i] + Spart[MI * MI + i] + Spart[2 * MI * MI + i]
            + Spart[3 * MI * MI + i] + Spart[4 * MI * MI + i];
    float v = F[i] * s;
    S[i] = v;
    M2[i] = Kuu[i] + INV_SIGMA2 * v;
}

// ---------------- G += psi1^T Y ----------------
__global__ void k_G(const float* __restrict__ psi1, const float* __restrict__ Y,
                    float* __restrict__ G) {
    int a = threadIdx.x;
    int n0 = blockIdx.x * 125;
    float acc[DOUT] = {};
    for (int n = n0; n < n0 + 125; ++n) {
        float p = psi1[n * MI + a];
        #pragma unroll
        for (int d = 0; d < DOUT; ++d) acc[d] += p * Y[n * DOUT + d];
    }
    #pragma unroll
    for (int d = 0; d < DOUT; ++d) atomicAdd(&G[a * DOUT + d], acc[d]);
}

// ---------------- 64x64 diag Cholesky + triangular inverse ------------------
// Register-tiled 4x4 cells (16 fl/thread - does NOT spill), 1 barrier/pivot
// via double-buffered column publish. Then forward-substitution inverse of
// the same block (1 barrier/step, double-buffered rowbuf), written to Li.
// L_dd itself is never needed downstream (trsm uses Linv_dd; cholu/toff only
// touch strictly-below-diagonal blocks), so it is not written to global.
__global__ void k_dchol(float* __restrict__ AK, float* __restrict__ AM,
                        float* __restrict__ LiK, float* __restrict__ LiM,
                        float* __restrict__ acc, int p) {
    float* A  = blockIdx.x ? AM : AK;
    float* Li = blockIdx.x ? LiM : LiK;
    const int c0 = 64 * p;
    __shared__ float colbuf[2][64];
    __shared__ float isbuf[64];
    __shared__ float LT[64 * 68];      // LT[c*68+r] = L[r][c]
    __shared__ float rowbuf[2][64];
    int tid = threadIdx.x;             // 256
    int tx = tid & 15, ty = tid >> 4;  // cell (4tx+i, 4ty+j)
    float t[4][4];
    #pragma unroll
    for (int i = 0; i < 4; ++i)
        #pragma unroll
        for (int j = 0; j < 4; ++j)
            t[i][j] = A[(c0 + 4 * tx + i) * MI + c0 + 4 * ty + j];
    if (ty == 0) {
        #pragma unroll
        for (int i = 0; i < 4; ++i) colbuf[0][4 * tx + i] = t[i][0];
    }
    __syncthreads();
    float lgsum = 0.f;
    for (int kk = 0; kk < 64; ++kk) {
        int pb = kk & 1;
        float piv = colbuf[pb][kk];
        float is2 = 1.0f / piv;
        if (tid == 0) { isbuf[kk] = rsqrtf(piv); lgsum += __logf(piv); }
        float ar[4], bc[4];
        #pragma unroll
        for (int i = 0; i < 4; ++i) { int r = 4 * tx + i; ar[i] = (r > kk) ? colbuf[pb][r] * is2 : 0.f; }
        #pragma unroll
        for (int j = 0; j < 4; ++j) { int c = 4 * ty + j; bc[j] = (c > kk) ? colbuf[pb][c] : 0.f; }
        #pragma unroll
        for (int i = 0; i < 4; ++i)
            #pragma unroll
            for (int j = 0; j < 4; ++j)
                t[i][j] = fmaf(-ar[i], bc[j], t[i][j]);
        if (kk < 63 && ty == ((kk + 1) >> 2)) {
            #pragma unroll
            for (int j = 0; j < 4; ++j) {
                if (4 * ty + j == kk + 1) {
                    #pragma unroll
                    for (int i = 0; i < 4; ++i)
                        colbuf[1 - pb][4 * tx + i] = t[i][j];
                }
            }
        }
        __syncthreads();
    }
    if (tid == 0) atomicAdd(&acc[2 + blockIdx.x], lgsum);
    // finalize L into LDS transposed: LT[c*68+r] = t * isbuf[c]  (upper = 0)
    #pragma unroll
    for (int i = 0; i < 4; ++i)
        #pragma unroll
        for (int j = 0; j < 4; ++j) {
            int r = 4 * tx + i, c = 4 * ty + j;
            LT[c * 68 + r] = (r >= c) ? t[i][j] * isbuf[c] : 0.f;
        }
    __syncthreads();
    // ---- inverse: X = L^-1 via forward substitution, cells x[4][4] ----
    float x[4][4];
    #pragma unroll
    for (int i = 0; i < 4; ++i)
        #pragma unroll
        for (int j = 0; j < 4; ++j)
            x[i][j] = (4 * tx + i == 4 * ty + j) ? 1.f : 0.f;
    for (int s = 0; s < 64; ++s) {
        int pb = s & 1;
        if (tx == (s >> 2)) {
            float dinv = 1.0f / LT[s * 68 + s];
            #pragma unroll
            for (int i = 0; i < 4; ++i) {
                if (4 * tx + i == s) {
                    #pragma unroll
                    for (int j = 0; j < 4; ++j) {
                        float v = x[i][j] * dinv;
                        x[i][j] = v;
                        rowbuf[pb][4 * ty + j] = v;
                    }
                }
            }
        }
        __syncthreads();
        float lc[4], rb[4];
        #pragma unroll
        for (int i = 0; i < 4; ++i) { int r = 4 * tx + i; lc[i] = (r > s) ? LT[s * 68 + r] : 0.f; }
        #pragma unroll
        for (int j = 0; j < 4; ++j) rb[j] = rowbuf[pb][4 * ty + j];
        #pragma unroll
        for (int i = 0; i < 4; ++i)
            #pragma unroll
            for (int j = 0; j < 4; ++j)
                x[i][j] = fmaf(-lc[i], rb[j], x[i][j]);
    }
    #pragma unroll
    for (int i = 0; i < 4; ++i)
        #pragma unroll
        for (int j = 0; j < 4; ++j)
            Li[(c0 + 4 * tx + i) * MI + c0 + 4 * ty + j] = x[i][j];
}

// ---------------- TRSM: L21 tile = A21 tile * Linv_dd^T ---------------------
__global__ void k_trsm(float* __restrict__ AK, float* __restrict__ AM,
                       const float* __restrict__ LiK, const float* __restrict__ LiM,
                       int p) {
    float* A = blockIdx.y ? AM : AK;
    const float* Li = blockIdx.y ? LiM : LiK;
    int c0 = 64 * p;
    int R0 = c0 + 64 + 64 * blockIdx.x;
    __shared__ float As[64 * 68], Bs[64 * 68];
    int tid = threadIdx.x;
    int tx = tid & 15, ty = tid >> 4;
    for (int q = tid; q < 4096; q += 256) {
        int rr = q >> 6, k = q & 63;
        As[k * 68 + rr] = A[(R0 + rr) * MI + c0 + k];
        Bs[k * 68 + rr] = Li[(c0 + rr) * MI + c0 + k];   // Bs[k][c] = Linv[c][k]
    }
    __syncthreads();
    float acc[4][4] = {};
    #pragma unroll 4
    for (int k = 0; k < 64; ++k) {
        float4 a4 = *(const float4*)&As[k * 68 + 4 * tx];
        float4 b4 = *(const float4*)&Bs[k * 68 + 4 * ty];
        float a[4] = {a4.x, a4.y, a4.z, a4.w};
        float b[4] = {b4.x, b4.y, b4.z, b4.w};
        #pragma unroll
        for (int i = 0; i < 4; ++i)
            #pragma unroll
            for (int j = 0; j < 4; ++j)
                acc[i][j] += a[i] * b[j];
    }
    #pragma unroll
    for (int i = 0; i < 4; ++i)
        #pragma unroll
        for (int j = 0; j < 4; ++j)
            A[(R0 + 4 * tx + i) * MI + c0 + 4 * ty + j] = acc[i][j];
}

// ---------------- trailing update: A22 -= Lp * Lp^T (64x64x64 tiles) --------
__global__ void k_cholu(float* __restrict__ AK, float* __restrict__ AM, int p) {
    float* A = blockIdx.y ? AM : AK;
    int t0 = 64 * (p + 1);
    int idx = blockIdx.x, ti = 0;
    while (idx > ti) { idx -= ti + 1; ti++; }
    int tj = idx;                            // lower tiles ti >= tj
    int R0 = t0 + 64 * ti, C0 = t0 + 64 * tj, K0 = 64 * p;
    __shared__ float As[64 * 68], Bs[64 * 68];
    int tid = threadIdx.x;
    int tx = tid & 15, ty = tid >> 4;
    for (int q = tid; q < 4096; q += 256) {
        int rr = q >> 6, k = q & 63;
        As[k * 68 + rr] = A[(R0 + rr) * MI + K0 + k];
        Bs[k * 68 + rr] = A[(C0 + rr) * MI + K0 + k];
    }
    __syncthreads();
    float acc[4][4] = {};
    #pragma unroll 4
    for (int k = 0; k < 64; ++k) {
        float4 a4 = *(const float4*)&As[k * 68 + 4 * tx];
        float4 b4 = *(const float4*)&Bs[k * 68 + 4 * ty];
        float a[4] = {a4.x, a4.y, a4.z, a4.w};
        float b[4] = {b4.x, b4.y, b4.z, b4.w};
        #pragma unroll
        for (int i = 0; i < 4; ++i)
            #pragma unroll
            for (int j = 0; j < 4; ++j)
                acc[i][j] += a[i] * b[j];
    }
    #pragma unroll
    for (int i = 0; i < 4; ++i)
        #pragma unroll
        for (int j = 0; j < 4; ++j) {
            int g = (R0 + 4 * tx + i) * MI + C0 + 4 * ty + j;
            A[g] -= acc[i][j];
        }
}

// ---- off-diagonal Linv blocks at distance d: X_ij = -Linv_ii * sum L_ik X_kj
__global__ void k_toff(const float* __restrict__ LAK, const float* __restrict__ LAM,
                       float* __restrict__ LiK, float* __restrict__ LiM, int d) {
    const float* LA = blockIdx.y ? LAM : LAK;
    float* Li = blockIdx.y ? LiM : LiK;
    int j = blockIdx.x, i = j + d;
    __shared__ float As[64 * 68], Bs[64 * 68];
    int tid = threadIdx.x;
    int tx = tid & 15, ty = tid >> 4;
    float acc[4][4] = {};
    for (int m = 0; m < d; ++m) {
        int kb = j + m;
        __syncthreads();
        for (int q = tid; q < 4096; q += 256) {
            int rr = q >> 6, k = q & 63;
            As[k * 68 + rr] = LA[(64 * i + rr) * MI + 64 * kb + k];
        }
        for (int q = tid; q < 4096; q += 256) {
            int k = q >> 6, c = q & 63;
            Bs[k * 68 + c] = Li[(64 * kb + k) * MI + 64 * j + c];
        }
        __syncthreads();
        #pragma unroll 4
        for (int k = 0; k < 64; ++k) {
            float4 a4 = *(const float4*)&As[k * 68 + 4 * tx];
            float4 b4 = *(const float4*)&Bs[k * 68 + 4 * ty];
            float a[4] = {a4.x, a4.y, a4.z, a4.w};
            float b[4] = {b4.x, b4.y, b4.z, b4.w};
            #pragma unroll
            for (int i2 = 0; i2 < 4; ++i2)
                #pragma unroll
                for (int j2 = 0; j2 < 4; ++j2)
                    acc[i2][j2] += a[i2] * b[j2];
        }
    }
    __syncthreads();
    #pragma unroll
    for (int i2 = 0; i2 < 4; ++i2)
        #pragma unroll
        for (int j2 = 0; j2 < 4; ++j2)
            Bs[(4 * tx + i2) * 68 + 4 * ty + j2] = acc[i2][j2];
    for (int q = tid; q < 4096; q += 256) {
        int rr = q >> 6, k = q & 63;
        As[k * 68 + rr] = Li[(64 * i + rr) * MI + 64 * i + k];
    }
    __syncthreads();
    float out[4][4] = {};
    #pragma unroll 4
    for (int k = 0; k < 64; ++k) {
        float4 a4 = *(const float4*)&As[k * 68 + 4 * tx];
        float4 b4 = *(const float4*)&Bs[k * 68 + 4 * ty];
        float a[4] = {a4.x, a4.y, a4.z, a4.w};
        float b[4] = {b4.x, b4.y, b4.z, b4.w};
        #pragma unroll
        for (int i2 = 0; i2 < 4; ++i2)
            #pragma unroll
            for (int j2 = 0; j2 < 4; ++j2)
                out[i2][j2] += a[i2] * b[j2];
    }
    #pragma unroll
    for (int i2 = 0; i2 < 4; ++i2)
        #pragma unroll
        for (int j2 = 0; j2 < 4; ++j2)
            Li[(64 * i + 4 * tx + i2) * MI + 64 * j + 4 * ty + j2] = -out[i2][j2];
}

// -------- trace(AAT)*sigma2 = <LinvK*S, LinvK>  (16 tiles, fused dot) -------
__global__ void k_trace(const float* __restrict__ Li, const float* __restrict__ S,
                        float* __restrict__ acc) {
    __shared__ __align__(16) float As[16 * 68], Bs[16 * 68];
    __shared__ float red[256];
    int tid = threadIdx.x;
    int R = 64 * (blockIdx.x >> 2), C = 64 * (blockIdx.x & 3);
    int tx = tid & 15, ty = tid >> 4;
    float acc4[4][4] = {};
    for (int k0 = 0; k0 < MI; k0 += 16) {
        __syncthreads();
        for (int q = tid; q < 1024; q += 256) {
            int rr = q >> 4, kk = q & 15;
            As[kk * 68 + rr] = Li[(R + rr) * MI + k0 + kk];
        }
        for (int q = tid; q < 1024; q += 256) {
            int kk = q >> 6, c = q & 63;
            Bs[kk * 68 + c] = S[(k0 + kk) * MI + C + c];
        }
        __syncthreads();
        #pragma unroll
        for (int k = 0; k < 16; ++k) {
            float4 a4 = *(const float4*)&As[k * 68 + 4 * tx];
            float4 b4 = *(const float4*)&Bs[k * 68 + 4 * ty];
            float a[4] = {a4.x, a4.y, a4.z, a4.w};
            float b[4] = {b4.x, b4.y, b4.z, b4.w};
            #pragma unroll
            for (int i = 0; i < 4; ++i)
                #pragma unroll
                for (int j = 0; j < 4; ++j)
                    acc4[i][j] += a[i] * b[j];
        }
    }
    float ts = 0.f;
    #pragma unroll
    for (int i = 0; i < 4; ++i)
        #pragma unroll
        for (int j = 0; j < 4; ++j)
            ts += acc4[i][j] * Li[(R + 4 * tx + i) * MI + C + 4 * ty + j];
    red[tid] = ts;
    __syncthreads();
    for (int st = 128; st > 0; st >>= 1) {
        if (tid < st) red[tid] += red[tid + st];
        __syncthreads();
    }
    if (tid == 0) atomicAdd(&acc[1], red[0]);
}

// -------- w = LinvM*G ; assemble bound ----------
__global__ void k_final(const float* __restrict__ LiM, const float* __restrict__ G,
                        const float* __restrict__ accbuf, const float* __restrict__ kvp,
                        float* __restrict__ out) {
    __shared__ float Gs[MI * DOUT];
    __shared__ float red[256];
    int tid = threadIdx.x;
    for (int i = tid; i < MI * DOUT; i += 256) Gs[i] = G[i];
    __syncthreads();
    float w[DOUT] = {};
    const float4* lrow4 = (const float4*)(LiM + tid * MI);
    for (int k4 = 0; k4 < MI / 4; ++k4) {
        float4 l = lrow4[k4];
        const float* g0 = &Gs[(4 * k4) * DOUT];
        #pragma unroll
        for (int d = 0; d < DOUT; ++d)
            w[d] += l.x * g0[d] + l.y * g0[DOUT + d] + l.z * g0[2 * DOUT + d] + l.w * g0[3 * DOUT + d];
    }
    float c2 = 0.f;
    #pragma unroll
    for (int d = 0; d < DOUT; ++d) c2 += w[d] * w[d];
    red[tid] = c2;
    __syncthreads();
    for (int st = 128; st > 0; st >>= 1) {
        if (tid < st) red[tid] += red[tid + st];
        __syncthreads();
    }
    if (tid == 0) {
        float kv = kvp[0];
        float trace = accbuf[1] * INV_SIGMA2;              // trace(AAT)
        float logdetB = accbuf[3] - accbuf[2];             // logdet(M2)-logdet(Kuu)
        float bound = -0.5f * (float)(NH * DOUT) * __logf(6.28318530717959f * SIGMA2)
                      - 0.5f * INV_SIGMA2 * accbuf[0]
                      - 0.5f * (float)DOUT * ((float)NH * kv * INV_SIGMA2 - trace)
                      - 0.5f * (float)DOUT * logdetB
                      + 0.5f * 1.0e6f * red[0];            // ||c||^2 = ||LinvM G||^2/sigma^4
        out[0] = bound;
    }
}

extern "C" void kernel_launch(void* const* d_in, const int* in_sizes, int n_in,
                              void* d_out, int out_size, void* d_ws, size_t ws_size,
                              hipStream_t stream) {
    (void)in_sizes; (void)n_in; (void)out_size; (void)ws_size;
    const float* Xm_m = (const float*)d_in[0];
    const float* Xm_v = (const float*)d_in[1];
    const float* Z    = (const float*)d_in[2];
    const float* Y    = (const float*)d_in[3];
    const float* kvp  = (const float*)d_in[4];
    const float* ls   = (const float*)d_in[5];
    float* out = (float*)d_out;
    float* W = (float*)d_ws;

    float* acc   = W;              // 16: [0]=sumY2 [1]=<LinvK S,LinvK> [2]=ldK [3]=ldM
    float* G     = W + 16;         // 4096
    float* LinvK = W + 4112;       // 65536
    float* LinvM = W + 69648;      // 65536   (zero range ends at 135184)
    float* vbar  = W + 135184;     // 80
    float* psi1  = W + 135264;     // 512000
    float* Eg    = W + 647264;     // 512000
    float* Kuu   = W + 1159264;    // 65536 (panels overwritten by L21 blocks)
    float* M2    = W + 1224800;    // 65536
    float* S     = W + 1290336;    // 65536 (psi2)
    float* F     = W + 1355872;    // 65536
    float* Spart = W + 1421408;    // 5*65536 (end ~7.0 MB)

    k_zero<<<529, 256, 0, stream>>>(W, 135184);            // acc, G, LinvK, LinvM
    k_prep<<<DIN + 8, 256, 0, stream>>>(Xm_v, Y, ls, vbar, acc);
    k_main<<<NH, 256, 0, stream>>>(Xm_m, Xm_v, Z, ls, kvp, psi1, Eg);
    k_kuuF<<<MI, 256, 0, stream>>>(Z, ls, vbar, kvp, Kuu, F);
    k_syrk<<<dim3(16, 5), 256, 0, stream>>>(Eg, Spart);
    k_psi2M<<<MI, 256, 0, stream>>>(F, Spart, Kuu, S, M2);
    k_G<<<16, 256, 0, stream>>>(psi1, Y, G);

    // batched blocked Cholesky + inline diag inverse of {Kuu, M2}
    for (int p = 0; p < 4; ++p) {
        k_dchol<<<2, 256, 0, stream>>>(Kuu, M2, LinvK, LinvM, acc, p);
        if (p < 3) {
            k_trsm<<<dim3(3 - p, 2), 256, 0, stream>>>(Kuu, M2, LinvK, LinvM, p);
            int nt = 3 - p;
            k_cholu<<<dim3(nt * (nt + 1) / 2, 2), 256, 0, stream>>>(Kuu, M2, p);
        }
    }
    // off-diagonal Linv blocks
    for (int d = 1; d < 4; ++d)
        k_toff<<<dim3(4 - d, 2), 256, 0, stream>>>(Kuu, M2, LinvK, LinvM, d);

    k_trace<<<16, 256, 0, stream>>>(LinvK, S, acc);
    k_final<<<1, 256, 0, stream>>>(LinvM, G, acc, kvp, out);
}